// Round 2
// baseline (1359.092 us; speedup 1.0000x reference)
//
#include <hip/hip_runtime.h>

// ---------------------------------------------------------------------------
// RWKV6 layer forward, MI355X. Round 1: all-fp32 I/O (reference is float32).
// Pipeline: ln2 -> xproj -> SGEMMs (r,k,v,g,w-lora) -> rbk -> WKV (3-pass
// chunked scan) -> groupnorm+gate -> o_W GEMM (+x0) -> ln1 -> ffnmix ->
// fk GEMM (relu^2) -> fv GEMM -> fr GEMM (sigmoid gate).
// Workspace: ~234 MB linear layout with buffer reuse.
// ---------------------------------------------------------------------------

#define DEVINL __device__ __forceinline__

constexpr int B_  = 8, T_ = 1024, NH_ = 4;
constexpr int BT_ = B_ * T_;          // 8192 tokens
constexpr float EPS_ = 1e-5f;
constexpr int CH_ = 32;               // WKV chunk length
constexpr int NC_ = T_ / CH_;         // 32 chunks per sequence

// block-wide sum over 256 threads (4 waves), result broadcast to all threads
DEVINL float block_sum256(float v, float* sb) {
  for (int o = 32; o; o >>= 1) v += __shfl_down(v, o);
  int w = threadIdx.x >> 6;
  __syncthreads();                       // protect sb from previous use
  if ((threadIdx.x & 63) == 0) sb[w] = v;
  __syncthreads();
  return sb[0] + sb[1] + sb[2] + sb[3];
}

// --------------------------- LN kernels ------------------------------------
// x -> x0 = LN(x, pre), h = LN(x0, attn)
__global__ __launch_bounds__(256) void ln2_kernel(
    const float* __restrict__ x,
    const float* __restrict__ pg, const float* __restrict__ pb,
    const float* __restrict__ ag, const float* __restrict__ ab,
    float* __restrict__ x0, float* __restrict__ h)
{
  __shared__ float sb[4];
  size_t base = (size_t)blockIdx.x * 512;
  int tid = threadIdx.x;
  float v0 = x[base + tid], v1 = x[base + 256 + tid];
  float m = block_sum256(v0 + v1, sb) * (1.f / 512.f);
  float d0 = v0 - m, d1 = v1 - m;
  float var = block_sum256(d0 * d0 + d1 * d1, sb) * (1.f / 512.f);
  float rs = rsqrtf(var + EPS_);
  float a0 = d0 * rs * pg[tid]       + pb[tid];
  float a1 = d1 * rs * pg[tid + 256] + pb[tid + 256];
  x0[base + tid] = a0; x0[base + 256 + tid] = a1;
  float m2 = block_sum256(a0 + a1, sb) * (1.f / 512.f);
  float e0 = a0 - m2, e1 = a1 - m2;
  float var2 = block_sum256(e0 * e0 + e1 * e1, sb) * (1.f / 512.f);
  float rs2 = rsqrtf(var2 + EPS_);
  h[base + tid]       = e0 * rs2 * ag[tid]       + ab[tid];
  h[base + 256 + tid] = e1 * rs2 * ag[tid + 256] + ab[tid + 256];
}

// single LN: res -> hf
__global__ __launch_bounds__(256) void ln1_kernel(
    const float* __restrict__ in,
    const float* __restrict__ g, const float* __restrict__ b,
    float* __restrict__ out)
{
  __shared__ float sb[4];
  size_t base = (size_t)blockIdx.x * 512;
  int tid = threadIdx.x;
  float v0 = in[base + tid], v1 = in[base + 256 + tid];
  float m = block_sum256(v0 + v1, sb) * (1.f / 512.f);
  float d0 = v0 - m, d1 = v1 - m;
  float var = block_sum256(d0 * d0 + d1 * d1, sb) * (1.f / 512.f);
  float rs = rsqrtf(var + EPS_);
  out[base + tid]       = d0 * rs * g[tid]       + b[tid];
  out[base + 256 + tid] = d1 * rs * g[tid + 256] + b[tid + 256];
}

// --------------------------- xproj -----------------------------------------
// per token: y = h + delta*mu; z5 = tanh(W1 y) [160]; for n in 0..4:
//   z_n = W2[:,n,:] z5_n + bias_n ; m_n = h + delta * z_n  -> m5[n][t][c]
__global__ __launch_bounds__(256) void xproj_kernel(
    const float* __restrict__ h, const float* __restrict__ mu,
    const float* __restrict__ W1, const float* __restrict__ W2,
    const float* __restrict__ xb, float* __restrict__ m5)
{
  __shared__ float hc[512], dl[512], y[512], z5[160];
  int t = blockIdx.x, tid = threadIdx.x, tt = t & (T_ - 1);
  for (int c = tid; c < 512; c += 256) {
    float cur  = h[(size_t)t * 512 + c];
    float prev = tt ? h[(size_t)(t - 1) * 512 + c] : 0.f;
    float d = prev - cur;
    hc[c] = cur; dl[c] = d;
    y[c] = cur + d * mu[c];
  }
  __syncthreads();
  if (tid < 160) {
    const float* wrow = &W1[(size_t)tid * 512];
    float acc = 0.f;
    for (int i = 0; i < 512; i += 8) {
      float4 w0 = *(const float4*)&wrow[i];
      float4 w1 = *(const float4*)&wrow[i + 4];
      float4 y0 = *(const float4*)&y[i];
      float4 y1 = *(const float4*)&y[i + 4];
      acc += w0.x * y0.x + w0.y * y0.y + w0.z * y0.z + w0.w * y0.w
           + w1.x * y1.x + w1.y * y1.y + w1.z * y1.z + w1.w * y1.w;
    }
    z5[tid] = tanhf(acc);
  }
  __syncthreads();
  for (int n = 0; n < 5; n++) {
    for (int c = tid; c < 512; c += 256) {
      const float* wrow = &W2[(size_t)c * 160 + n * 32];
      float acc = xb[n * 512 + c];
      for (int r = 0; r < 32; r += 8) {
        float4 w0 = *(const float4*)&wrow[r];
        float4 w1 = *(const float4*)&wrow[r + 4];
        const float* zz = &z5[n * 32 + r];
        acc += w0.x * zz[0] + w0.y * zz[1] + w0.z * zz[2] + w0.w * zz[3]
             + w1.x * zz[4] + w1.y * zz[5] + w1.z * zz[6] + w1.w * zz[7];
      }
      m5[((size_t)n * BT_ + t) * 512 + c] = hc[c] + dl[c] * acc;
    }
  }
}

// --------------------------- generic SGEMM ---------------------------------
// C[M,N] = epi(A[M,K] @ W[N,K]^T). A,W fp32 row-major.
// 64x64 tile, BK=16, 256 threads, 4x4 per thread. M%64==0, N%64==0, K%16==0.
enum { EPI_NONE = 0, EPI_TANH = 1, EPI_EXPEXP = 2, EPI_RES = 3, EPI_RELU2 = 4, EPI_OUT = 5 };

template <int EPI>
__global__ __launch_bounds__(256) void sgemm_nt(
    const float* __restrict__ A, const float* __restrict__ W,
    float* __restrict__ C, int M, int N, int K,
    const float* __restrict__ bias,
    const float* __restrict__ aux1, const float* __restrict__ aux2)
{
  __shared__ float As[16][68];   // [k][m], padded stride 68 (16B aligned rows)
  __shared__ float Ws[16][68];   // [k][n]
  int m0 = blockIdx.x * 64, n0 = blockIdx.y * 64;
  int tid = threadIdx.x;
  int tx = tid & 15, ty = tid >> 4;
  int lr = tid >> 2;             // 0..63 row within tile
  int lk = (tid & 3) * 4;        // 0,4,8,12
  float acc[4][4] = {};
  for (int kb = 0; kb < K; kb += 16) {
    float4 av = *(const float4*)&A[(size_t)(m0 + lr) * K + kb + lk];
    float4 wv = *(const float4*)&W[(size_t)(n0 + lr) * K + kb + lk];
    __syncthreads();
    As[lk + 0][lr] = av.x; As[lk + 1][lr] = av.y;
    As[lk + 2][lr] = av.z; As[lk + 3][lr] = av.w;
    Ws[lk + 0][lr] = wv.x; Ws[lk + 1][lr] = wv.y;
    Ws[lk + 2][lr] = wv.z; Ws[lk + 3][lr] = wv.w;
    __syncthreads();
#pragma unroll
    for (int kk = 0; kk < 16; kk++) {
      float4 a4 = *(const float4*)&As[kk][ty * 4];
      float4 w4 = *(const float4*)&Ws[kk][tx * 4];
      float am[4] = {a4.x, a4.y, a4.z, a4.w};
      float wn[4] = {w4.x, w4.y, w4.z, w4.w};
#pragma unroll
      for (int im = 0; im < 4; im++)
#pragma unroll
        for (int in_ = 0; in_ < 4; in_++)
          acc[im][in_] += am[im] * wn[in_];
    }
  }
#pragma unroll
  for (int im = 0; im < 4; im++) {
    int m = m0 + ty * 4 + im;
    size_t off = (size_t)m * N + n0 + tx * 4;
    float c0 = acc[im][0], c1 = acc[im][1], c2 = acc[im][2], c3 = acc[im][3];
    if constexpr (EPI == EPI_TANH) {
      c0 = tanhf(c0); c1 = tanhf(c1); c2 = tanhf(c2); c3 = tanhf(c3);
    } else if constexpr (EPI == EPI_EXPEXP) {
      int n = n0 + tx * 4;
      c0 = expf(-expf(c0 + bias[n + 0]));
      c1 = expf(-expf(c1 + bias[n + 1]));
      c2 = expf(-expf(c2 + bias[n + 2]));
      c3 = expf(-expf(c3 + bias[n + 3]));
    } else if constexpr (EPI == EPI_RES) {
      float4 xv = *(const float4*)&aux1[off];
      c0 += xv.x; c1 += xv.y; c2 += xv.z; c3 += xv.w;
    } else if constexpr (EPI == EPI_RELU2) {
      c0 = fmaxf(c0, 0.f); c0 *= c0;
      c1 = fmaxf(c1, 0.f); c1 *= c1;
      c2 = fmaxf(c2, 0.f); c2 *= c2;
      c3 = fmaxf(c3, 0.f); c3 *= c3;
    } else if constexpr (EPI == EPI_OUT) {
      float4 rv = *(const float4*)&aux1[off];   // res
      float4 vv = *(const float4*)&aux2[off];   // val
      c0 = rv.x + vv.x * (1.f / (1.f + expf(-c0)));
      c1 = rv.y + vv.y * (1.f / (1.f + expf(-c1)));
      c2 = rv.z + vv.z * (1.f / (1.f + expf(-c2)));
      c3 = rv.w + vv.w * (1.f / (1.f + expf(-c3)));
    }
    float4 cv; cv.x = c0; cv.y = c1; cv.z = c2; cv.w = c3;
    *(float4*)&C[off] = cv;
  }
}

// --------------------------- bonus scalar ----------------------------------
// rbk[t,h] = sum_k r[t,h,k]*bonus[h,k]*k[t,h,k]
__global__ __launch_bounds__(256) void rbk_kernel(
    const float* __restrict__ r, const float* __restrict__ k,
    const float* __restrict__ bonus, float* __restrict__ rbk)
{
  int t = blockIdx.x, tid = threadIdx.x;
  int hh = tid >> 6, j = tid & 63;
  size_t g = (size_t)t * 256 + hh * 64 + j;
  float p = r[g] * k[g] * bonus[hh * 64 + j];
  for (int o = 32; o; o >>= 1) p += __shfl_down(p, o);
  if (j == 0) rbk[(size_t)t * 4 + hh] = p;
}

// --------------------------- WKV 3-pass chunked scan ------------------------
// state S[HK=64][HV=128] per (b,head). Thread vi owns column vi (64 regs).
// pass1: per chunk from S=0: S_local and decay product D.
__global__ __launch_bounds__(128) void wkv_pass1(
    const float* __restrict__ k, const float* __restrict__ ew,
    const float* __restrict__ v, float* __restrict__ Sl, float* __restrict__ Dp)
{
  __shared__ float kL[CH_][64], eL[CH_][64], vL[CH_][128];
  int blk = blockIdx.x;
  int c = blk & (NC_ - 1), bh = blk >> 5;
  int b = bh >> 2, hh = bh & 3;
  int tid = threadIdx.x;
  size_t tbase = (size_t)b * T_ + (size_t)c * CH_;
  for (int idx = tid; idx < CH_ * 64; idx += 128) {
    int s = idx >> 6, j = idx & 63;
    size_t g = (tbase + s) * 256 + hh * 64 + j;
    kL[s][j] = k[g]; eL[s][j] = ew[g];
  }
  for (int idx = tid; idx < CH_ * 128; idx += 128) {
    int s = idx >> 7, vi = idx & 127;
    vL[s][vi] = v[(tbase + s) * 512 + hh * 128 + vi];
  }
  __syncthreads();
  float S[64];
#pragma unroll
  for (int j = 0; j < 64; j++) S[j] = 0.f;
  for (int s = 0; s < CH_; s++) {
    float vv = vL[s][tid];
    const float4* e4p = (const float4*)&eL[s][0];
    const float4* k4p = (const float4*)&kL[s][0];
#pragma unroll
    for (int q = 0; q < 16; q++) {
      float4 e4 = e4p[q], k4 = k4p[q];
      S[4 * q + 0] = e4.x * S[4 * q + 0] + k4.x * vv;
      S[4 * q + 1] = e4.y * S[4 * q + 1] + k4.y * vv;
      S[4 * q + 2] = e4.z * S[4 * q + 2] + k4.z * vv;
      S[4 * q + 3] = e4.w * S[4 * q + 3] + k4.w * vv;
    }
  }
  size_t sbase = (size_t)blk * 8192;
#pragma unroll
  for (int j = 0; j < 64; j++) Sl[sbase + j * 128 + tid] = S[j];
  if (tid < 64) {
    float d = 1.f;
    for (int s = 0; s < CH_; s++) d *= eL[s][tid];
    Dp[(size_t)blk * 64 + tid] = d;
  }
}

// pass2: independent scan per state element across chunks. Ss[c] = state before chunk c.
__global__ __launch_bounds__(256) void wkv_scan(
    const float* __restrict__ Sl, const float* __restrict__ Dp, float* __restrict__ Ss)
{
  int e = blockIdx.x * 256 + threadIdx.x;   // < 32*8192
  int bh = e >> 13; int kv = e & 8191; int j = kv >> 7;
  float run = 0.f;
  for (int c = 0; c < NC_; c++) {
    size_t base = (size_t)bh * NC_ + c;
    Ss[base * 8192 + kv] = run;
    run = Dp[base * 64 + j] * run + Sl[base * 8192 + kv];
  }
}

// pass3: replay chunk from true initial state, emit o.
__global__ __launch_bounds__(128) void wkv_pass3(
    const float* __restrict__ r, const float* __restrict__ k,
    const float* __restrict__ ew, const float* __restrict__ v,
    const float* __restrict__ rbk, const float* __restrict__ Ss,
    float* __restrict__ o)
{
  __shared__ float rL[CH_][64], kL[CH_][64], eL[CH_][64], vL[CH_][128], rbL[CH_];
  int blk = blockIdx.x;
  int c = blk & (NC_ - 1), bh = blk >> 5;
  int b = bh >> 2, hh = bh & 3;
  int tid = threadIdx.x;
  size_t tbase = (size_t)b * T_ + (size_t)c * CH_;
  for (int idx = tid; idx < CH_ * 64; idx += 128) {
    int s = idx >> 6, j = idx & 63;
    size_t g = (tbase + s) * 256 + hh * 64 + j;
    rL[s][j] = r[g]; kL[s][j] = k[g]; eL[s][j] = ew[g];
  }
  for (int idx = tid; idx < CH_ * 128; idx += 128) {
    int s = idx >> 7, vi = idx & 127;
    vL[s][vi] = v[(tbase + s) * 512 + hh * 128 + vi];
  }
  if (tid < CH_) rbL[tid] = rbk[(tbase + tid) * 4 + hh];
  __syncthreads();
  float S[64];
  size_t sbase = (size_t)blk * 8192;
#pragma unroll
  for (int j = 0; j < 64; j++) S[j] = Ss[sbase + j * 128 + tid];
  for (int s = 0; s < CH_; s++) {
    float vv = vL[s][tid];
    float oa = rbL[s] * vv;
    const float4* r4p = (const float4*)&rL[s][0];
    const float4* e4p = (const float4*)&eL[s][0];
    const float4* k4p = (const float4*)&kL[s][0];
#pragma unroll
    for (int q = 0; q < 16; q++) {
      float4 r4 = r4p[q], e4 = e4p[q], k4 = k4p[q];
      oa += r4.x * S[4 * q + 0] + r4.y * S[4 * q + 1]
          + r4.z * S[4 * q + 2] + r4.w * S[4 * q + 3];
      S[4 * q + 0] = e4.x * S[4 * q + 0] + k4.x * vv;
      S[4 * q + 1] = e4.y * S[4 * q + 1] + k4.y * vv;
      S[4 * q + 2] = e4.z * S[4 * q + 2] + k4.z * vv;
      S[4 * q + 3] = e4.w * S[4 * q + 3] + k4.w * vv;
    }
    o[(tbase + s) * 512 + hh * 128 + tid] = oa;
  }
}

// --------------------------- groupnorm + swish gate -------------------------
__global__ __launch_bounds__(256) void gn_gate_kernel(
    float* __restrict__ o, const float* __restrict__ g,
    const float* __restrict__ gg, const float* __restrict__ gb)
{
  __shared__ float ov[512], ps[64], qs[64], mh[4], vh[4];
  int t = blockIdx.x, tid = threadIdx.x;
  size_t base = (size_t)t * 512;
  ov[tid] = o[base + tid]; ov[tid + 256] = o[base + 256 + tid];
  __syncthreads();
  if (tid < 64) {
    int hh = tid >> 4, sg = tid & 15;
    const float* p = &ov[hh * 128 + sg * 8];
    float s = 0.f, q = 0.f;
    for (int i = 0; i < 8; i++) { s += p[i]; q += p[i] * p[i]; }
    ps[tid] = s; qs[tid] = q;
  }
  __syncthreads();
  if (tid < 4) {
    float s = 0.f, q = 0.f;
    for (int i = 0; i < 16; i++) { s += ps[tid * 16 + i]; q += qs[tid * 16 + i]; }
    float m = s * (1.f / 128.f);
    mh[tid] = m; vh[tid] = q * (1.f / 128.f) - m * m;
  }
  __syncthreads();
  for (int c = tid; c < 512; c += 256) {
    int hh = c >> 7;
    float nrm = (ov[c] - mh[hh]) * rsqrtf(vh[hh] + EPS_);
    float gv = g[base + c];
    float sw = gv * (1.f / (1.f + expf(-gv)));
    o[base + c] = (nrm * gg[c] + gb[c]) * sw;
  }
}

// --------------------------- FFN token-shift mix ----------------------------
__global__ __launch_bounds__(256) void ffnmix_kernel(
    const float* __restrict__ hf, const float* __restrict__ fkmu,
    const float* __restrict__ frmu,
    float* __restrict__ mfk, float* __restrict__ mfr)
{
  int t = blockIdx.x, tid = threadIdx.x, tt = t & (T_ - 1);
  size_t base = (size_t)t * 512;
  for (int c = tid; c < 512; c += 256) {
    float cur  = hf[base + c];
    float prev = tt ? hf[base - 512 + c] : 0.f;
    float d = prev - cur;
    mfk[base + c] = cur + d * fkmu[c];
    mfr[base + c] = cur + d * frmu[c];
  }
}

// ---------------------------------------------------------------------------
extern "C" void kernel_launch(void* const* d_in, const int* in_sizes, int n_in,
                              void* d_out, int out_size, void* d_ws, size_t ws_size,
                              hipStream_t stream) {
  (void)in_sizes; (void)n_in; (void)out_size; (void)ws_size;
  const float* x        = (const float*)d_in[0];
  const float* pre_g    = (const float*)d_in[1];
  const float* pre_b    = (const float*)d_in[2];
  const float* attn_g   = (const float*)d_in[3];
  const float* attn_b   = (const float*)d_in[4];
  const float* ffn_g    = (const float*)d_in[5];
  const float* ffn_b    = (const float*)d_in[6];
  const float* xproj_mu = (const float*)d_in[7];
  const float* xproj_w1 = (const float*)d_in[8];
  const float* xproj_w2 = (const float*)d_in[9];
  const float* x_bias   = (const float*)d_in[10];
  const float* r_W      = (const float*)d_in[11];
  const float* w_W1     = (const float*)d_in[12];
  const float* w_W2     = (const float*)d_in[13];
  const float* w_b      = (const float*)d_in[14];
  const float* k_W      = (const float*)d_in[15];
  const float* v_W      = (const float*)d_in[16];
  const float* g_W      = (const float*)d_in[17];
  const float* bonus    = (const float*)d_in[18];
  const float* gnorm_g  = (const float*)d_in[19];
  const float* gnorm_b  = (const float*)d_in[20];
  const float* o_W      = (const float*)d_in[21];
  const float* fk_mu    = (const float*)d_in[22];
  const float* fk_W     = (const float*)d_in[23];
  const float* fv_W     = (const float*)d_in[24];
  const float* fr_mu    = (const float*)d_in[25];
  const float* fr_W     = (const float*)d_in[26];

  const size_t BTH = (size_t)BT_ * 512;  // 4,194,304
  size_t cur = 0;
  auto alloc = [&](size_t nf) { float* p = (float*)((char*)d_ws + cur); cur += nf * 4; return p; };
  float* x0   = alloc(BTH);
  float* hbuf = alloc(BTH);
  float* m5   = alloc(5 * BTH);          // slots: m_r,m_w,m_k,m_v,m_g
  float* rbuf = alloc((size_t)BT_ * 256);
  float* kbuf = alloc((size_t)BT_ * 256);
  float* ebuf = alloc((size_t)BT_ * 256);
  float* vbuf = alloc(BTH);
  float* gbuf = alloc(BTH);
  float* wtmp = alloc((size_t)BT_ * 64);
  float* rbk  = alloc((size_t)BT_ * 4);
  float* Sl   = alloc((size_t)32 * 32 * 8192);
  float* Ss   = alloc((size_t)32 * 32 * 8192);
  float* Dp   = alloc((size_t)32 * 32 * 64);
  // reuse (all original occupants dead by time of write):
  float* obuf = m5;                      // slot0 (m_r)
  float* res  = m5 + BTH;                // slot1 (m_w)
  float* hf   = m5 + 2 * BTH;            // slot2 (m_k)
  float* mfk  = m5 + 3 * BTH;            // slot3 (m_v)
  float* mfr  = m5 + 4 * BTH;            // slot4 (m_g)
  float* kkb  = Sl;                      // 8192x1024 f32
  float* valb = Ss;                      // 8192x512 f32

  ln2_kernel<<<BT_, 256, 0, stream>>>(x, pre_g, pre_b, attn_g, attn_b, x0, hbuf);
  xproj_kernel<<<BT_, 256, 0, stream>>>(hbuf, xproj_mu, xproj_w1, xproj_w2, x_bias, m5);

  sgemm_nt<EPI_NONE><<<dim3(128, 4), 256, 0, stream>>>(m5 + 0 * BTH, r_W, rbuf, BT_, 256, 512, nullptr, nullptr, nullptr);
  sgemm_nt<EPI_TANH><<<dim3(128, 1), 256, 0, stream>>>(m5 + 1 * BTH, w_W1, wtmp, BT_, 64, 512, nullptr, nullptr, nullptr);
  sgemm_nt<EPI_EXPEXP><<<dim3(128, 4), 256, 0, stream>>>(wtmp, w_W2, ebuf, BT_, 256, 64, w_b, nullptr, nullptr);
  sgemm_nt<EPI_NONE><<<dim3(128, 4), 256, 0, stream>>>(m5 + 2 * BTH, k_W, kbuf, BT_, 256, 512, nullptr, nullptr, nullptr);
  sgemm_nt<EPI_NONE><<<dim3(128, 8), 256, 0, stream>>>(m5 + 3 * BTH, v_W, vbuf, BT_, 512, 512, nullptr, nullptr, nullptr);
  sgemm_nt<EPI_NONE><<<dim3(128, 8), 256, 0, stream>>>(m5 + 4 * BTH, g_W, gbuf, BT_, 512, 512, nullptr, nullptr, nullptr);

  rbk_kernel<<<BT_, 256, 0, stream>>>(rbuf, kbuf, bonus, rbk);
  wkv_pass1<<<1024, 128, 0, stream>>>(kbuf, ebuf, vbuf, Sl, Dp);
  wkv_scan<<<1024, 256, 0, stream>>>(Sl, Dp, Ss);
  wkv_pass3<<<1024, 128, 0, stream>>>(rbuf, kbuf, ebuf, vbuf, rbk, Ss, obuf);

  gn_gate_kernel<<<BT_, 256, 0, stream>>>(obuf, gbuf, gnorm_g, gnorm_b);
  sgemm_nt<EPI_RES><<<dim3(128, 8), 256, 0, stream>>>(obuf, o_W, res, BT_, 512, 512, nullptr, x0, nullptr);

  ln1_kernel<<<BT_, 256, 0, stream>>>(res, ffn_g, ffn_b, hf);
  ffnmix_kernel<<<BT_, 256, 0, stream>>>(hf, fk_mu, fr_mu, mfk, mfr);
  sgemm_nt<EPI_RELU2><<<dim3(128, 16), 256, 0, stream>>>(mfk, fk_W, kkb, BT_, 1024, 512, nullptr, nullptr, nullptr);
  sgemm_nt<EPI_NONE><<<dim3(128, 8), 256, 0, stream>>>(kkb, fv_W, valb, BT_, 512, 1024, nullptr, nullptr, nullptr);
  sgemm_nt<EPI_OUT><<<dim3(128, 8), 256, 0, stream>>>(mfr, fr_W, (float*)d_out, BT_, 512, 512, nullptr, res, valb);
}

// Round 3
// 898.833 us; speedup vs baseline: 1.5121x; 1.5121x over previous
//
#include <hip/hip_runtime.h>

// ---------------------------------------------------------------------------
// RWKV6 layer forward, MI355X. Round 2: xproj GEMM-ified (was 45% of runtime
// as a latency-bound monolith). Everything else unchanged from round 1.
// ---------------------------------------------------------------------------

#define DEVINL __device__ __forceinline__

constexpr int B_  = 8, T_ = 1024, NH_ = 4;
constexpr int BT_ = B_ * T_;          // 8192 tokens
constexpr float EPS_ = 1e-5f;
constexpr int CH_ = 32;               // WKV chunk length
constexpr int NC_ = T_ / CH_;         // 32 chunks per sequence

// block-wide sum over 256 threads (4 waves), result broadcast to all threads
DEVINL float block_sum256(float v, float* sb) {
  for (int o = 32; o; o >>= 1) v += __shfl_down(v, o);
  int w = threadIdx.x >> 6;
  __syncthreads();                       // protect sb from previous use
  if ((threadIdx.x & 63) == 0) sb[w] = v;
  __syncthreads();
  return sb[0] + sb[1] + sb[2] + sb[3];
}

// --------------------------- LN kernels ------------------------------------
__global__ __launch_bounds__(256) void ln2_kernel(
    const float* __restrict__ x,
    const float* __restrict__ pg, const float* __restrict__ pb,
    const float* __restrict__ ag, const float* __restrict__ ab,
    float* __restrict__ x0, float* __restrict__ h)
{
  __shared__ float sb[4];
  size_t base = (size_t)blockIdx.x * 512;
  int tid = threadIdx.x;
  float v0 = x[base + tid], v1 = x[base + 256 + tid];
  float m = block_sum256(v0 + v1, sb) * (1.f / 512.f);
  float d0 = v0 - m, d1 = v1 - m;
  float var = block_sum256(d0 * d0 + d1 * d1, sb) * (1.f / 512.f);
  float rs = rsqrtf(var + EPS_);
  float a0 = d0 * rs * pg[tid]       + pb[tid];
  float a1 = d1 * rs * pg[tid + 256] + pb[tid + 256];
  x0[base + tid] = a0; x0[base + 256 + tid] = a1;
  float m2 = block_sum256(a0 + a1, sb) * (1.f / 512.f);
  float e0 = a0 - m2, e1 = a1 - m2;
  float var2 = block_sum256(e0 * e0 + e1 * e1, sb) * (1.f / 512.f);
  float rs2 = rsqrtf(var2 + EPS_);
  h[base + tid]       = e0 * rs2 * ag[tid]       + ab[tid];
  h[base + 256 + tid] = e1 * rs2 * ag[tid + 256] + ab[tid + 256];
}

__global__ __launch_bounds__(256) void ln1_kernel(
    const float* __restrict__ in,
    const float* __restrict__ g, const float* __restrict__ b,
    float* __restrict__ out)
{
  __shared__ float sb[4];
  size_t base = (size_t)blockIdx.x * 512;
  int tid = threadIdx.x;
  float v0 = in[base + tid], v1 = in[base + 256 + tid];
  float m = block_sum256(v0 + v1, sb) * (1.f / 512.f);
  float d0 = v0 - m, d1 = v1 - m;
  float var = block_sum256(d0 * d0 + d1 * d1, sb) * (1.f / 512.f);
  float rs = rsqrtf(var + EPS_);
  out[base + tid]       = d0 * rs * g[tid]       + b[tid];
  out[base + 256 + tid] = d1 * rs * g[tid + 256] + b[tid + 256];
}

// --------------------------- xproj (GEMM-ified) -----------------------------
// ymix: y = h + delta*mu, dl = delta (token shift within each sequence)
__global__ __launch_bounds__(256) void ymix_kernel(
    const float* __restrict__ h, const float* __restrict__ mu,
    float* __restrict__ y, float* __restrict__ dl)
{
  int t = blockIdx.x, tid = threadIdx.x, tt = t & (T_ - 1);
  size_t base = (size_t)t * 512;
  for (int c = tid; c < 512; c += 256) {
    float cur  = h[base + c];
    float prev = tt ? h[base - 512 + c] : 0.f;
    float d = prev - cur;
    dl[base + c] = d;
    y[base + c] = cur + d * mu[c];
  }
}

// pad W1 [160x512] -> [192x512] with zero rows
__global__ __launch_bounds__(256) void w1pad_kernel(
    const float* __restrict__ W1, float* __restrict__ W1p)
{
  int i = blockIdx.x * 256 + threadIdx.x;   // < 192*512
  int r = i >> 9;
  W1p[i] = (r < 160) ? W1[i] : 0.f;
}

// --------------------------- generic SGEMM ---------------------------------
// C[M,N] = epi(A[M,K] @ W[N,K]^T). A,W fp32 row-major with explicit strides.
// 64x64 tile, BK=16, 256 threads, 4x4 per thread. M%64==0, N%64==0, K%16==0.
enum { EPI_NONE = 0, EPI_TANH = 1, EPI_EXPEXP = 2, EPI_RES = 3, EPI_RELU2 = 4,
       EPI_OUT = 5, EPI_XMIX = 6 };

template <int EPI>
__global__ __launch_bounds__(256) void sgemm_nt(
    const float* __restrict__ A, const float* __restrict__ W,
    float* __restrict__ C, int M, int N, int K,
    int lda, int ldw, int ldc,
    const float* __restrict__ bias,
    const float* __restrict__ aux1, const float* __restrict__ aux2)
{
  __shared__ float As[16][68];   // [k][m], padded stride 68
  __shared__ float Ws[16][68];   // [k][n]
  int m0 = blockIdx.x * 64, n0 = blockIdx.y * 64;
  int tid = threadIdx.x;
  int tx = tid & 15, ty = tid >> 4;
  int lr = tid >> 2;             // 0..63 row within tile
  int lk = (tid & 3) * 4;        // 0,4,8,12
  float acc[4][4] = {};
  for (int kb = 0; kb < K; kb += 16) {
    float4 av = *(const float4*)&A[(size_t)(m0 + lr) * lda + kb + lk];
    float4 wv = *(const float4*)&W[(size_t)(n0 + lr) * ldw + kb + lk];
    __syncthreads();
    As[lk + 0][lr] = av.x; As[lk + 1][lr] = av.y;
    As[lk + 2][lr] = av.z; As[lk + 3][lr] = av.w;
    Ws[lk + 0][lr] = wv.x; Ws[lk + 1][lr] = wv.y;
    Ws[lk + 2][lr] = wv.z; Ws[lk + 3][lr] = wv.w;
    __syncthreads();
#pragma unroll
    for (int kk = 0; kk < 16; kk++) {
      float4 a4 = *(const float4*)&As[kk][ty * 4];
      float4 w4 = *(const float4*)&Ws[kk][tx * 4];
      float am[4] = {a4.x, a4.y, a4.z, a4.w};
      float wn[4] = {w4.x, w4.y, w4.z, w4.w};
#pragma unroll
      for (int im = 0; im < 4; im++)
#pragma unroll
        for (int in_ = 0; in_ < 4; in_++)
          acc[im][in_] += am[im] * wn[in_];
    }
  }
#pragma unroll
  for (int im = 0; im < 4; im++) {
    int m = m0 + ty * 4 + im;
    size_t off = (size_t)m * ldc + n0 + tx * 4;
    float c0 = acc[im][0], c1 = acc[im][1], c2 = acc[im][2], c3 = acc[im][3];
    if constexpr (EPI == EPI_TANH) {
      c0 = tanhf(c0); c1 = tanhf(c1); c2 = tanhf(c2); c3 = tanhf(c3);
    } else if constexpr (EPI == EPI_EXPEXP) {
      int n = n0 + tx * 4;
      c0 = expf(-expf(c0 + bias[n + 0]));
      c1 = expf(-expf(c1 + bias[n + 1]));
      c2 = expf(-expf(c2 + bias[n + 2]));
      c3 = expf(-expf(c3 + bias[n + 3]));
    } else if constexpr (EPI == EPI_RES) {
      float4 xv = *(const float4*)&aux1[off];
      c0 += xv.x; c1 += xv.y; c2 += xv.z; c3 += xv.w;
    } else if constexpr (EPI == EPI_RELU2) {
      c0 = fmaxf(c0, 0.f); c0 *= c0;
      c1 = fmaxf(c1, 0.f); c1 *= c1;
      c2 = fmaxf(c2, 0.f); c2 *= c2;
      c3 = fmaxf(c3, 0.f); c3 *= c3;
    } else if constexpr (EPI == EPI_OUT) {
      float4 rv = *(const float4*)&aux1[off];   // res
      float4 vv = *(const float4*)&aux2[off];   // val
      c0 = rv.x + vv.x * (1.f / (1.f + expf(-c0)));
      c1 = rv.y + vv.y * (1.f / (1.f + expf(-c1)));
      c2 = rv.z + vv.z * (1.f / (1.f + expf(-c2)));
      c3 = rv.w + vv.w * (1.f / (1.f + expf(-c3)));
    } else if constexpr (EPI == EPI_XMIX) {
      // m5 = h + dl * (acc + bias_n)
      float4 hv = *(const float4*)&aux1[off];   // h
      float4 dv = *(const float4*)&aux2[off];   // dl
      int n = n0 + tx * 4;
      c0 = hv.x + dv.x * (c0 + bias[n + 0]);
      c1 = hv.y + dv.y * (c1 + bias[n + 1]);
      c2 = hv.z + dv.z * (c2 + bias[n + 2]);
      c3 = hv.w + dv.w * (c3 + bias[n + 3]);
    }
    float4 cv; cv.x = c0; cv.y = c1; cv.z = c2; cv.w = c3;
    *(float4*)&C[off] = cv;
  }
}

// --------------------------- bonus scalar ----------------------------------
__global__ __launch_bounds__(256) void rbk_kernel(
    const float* __restrict__ r, const float* __restrict__ k,
    const float* __restrict__ bonus, float* __restrict__ rbk)
{
  int t = blockIdx.x, tid = threadIdx.x;
  int hh = tid >> 6, j = tid & 63;
  size_t g = (size_t)t * 256 + hh * 64 + j;
  float p = r[g] * k[g] * bonus[hh * 64 + j];
  for (int o = 32; o; o >>= 1) p += __shfl_down(p, o);
  if (j == 0) rbk[(size_t)t * 4 + hh] = p;
}

// --------------------------- WKV 3-pass chunked scan ------------------------
__global__ __launch_bounds__(128) void wkv_pass1(
    const float* __restrict__ k, const float* __restrict__ ew,
    const float* __restrict__ v, float* __restrict__ Sl, float* __restrict__ Dp)
{
  __shared__ float kL[CH_][64], eL[CH_][64], vL[CH_][128];
  int blk = blockIdx.x;
  int c = blk & (NC_ - 1), bh = blk >> 5;
  int b = bh >> 2, hh = bh & 3;
  int tid = threadIdx.x;
  size_t tbase = (size_t)b * T_ + (size_t)c * CH_;
  for (int idx = tid; idx < CH_ * 64; idx += 128) {
    int s = idx >> 6, j = idx & 63;
    size_t g = (tbase + s) * 256 + hh * 64 + j;
    kL[s][j] = k[g]; eL[s][j] = ew[g];
  }
  for (int idx = tid; idx < CH_ * 128; idx += 128) {
    int s = idx >> 7, vi = idx & 127;
    vL[s][vi] = v[(tbase + s) * 512 + hh * 128 + vi];
  }
  __syncthreads();
  float S[64];
#pragma unroll
  for (int j = 0; j < 64; j++) S[j] = 0.f;
  for (int s = 0; s < CH_; s++) {
    float vv = vL[s][tid];
    const float4* e4p = (const float4*)&eL[s][0];
    const float4* k4p = (const float4*)&kL[s][0];
#pragma unroll
    for (int q = 0; q < 16; q++) {
      float4 e4 = e4p[q], k4 = k4p[q];
      S[4 * q + 0] = e4.x * S[4 * q + 0] + k4.x * vv;
      S[4 * q + 1] = e4.y * S[4 * q + 1] + k4.y * vv;
      S[4 * q + 2] = e4.z * S[4 * q + 2] + k4.z * vv;
      S[4 * q + 3] = e4.w * S[4 * q + 3] + k4.w * vv;
    }
  }
  size_t sbase = (size_t)blk * 8192;
#pragma unroll
  for (int j = 0; j < 64; j++) Sl[sbase + j * 128 + tid] = S[j];
  if (tid < 64) {
    float d = 1.f;
    for (int s = 0; s < CH_; s++) d *= eL[s][tid];
    Dp[(size_t)blk * 64 + tid] = d;
  }
}

__global__ __launch_bounds__(256) void wkv_scan(
    const float* __restrict__ Sl, const float* __restrict__ Dp, float* __restrict__ Ss)
{
  int e = blockIdx.x * 256 + threadIdx.x;   // < 32*8192
  int bh = e >> 13; int kv = e & 8191; int j = kv >> 7;
  float run = 0.f;
  for (int c = 0; c < NC_; c++) {
    size_t base = (size_t)bh * NC_ + c;
    Ss[base * 8192 + kv] = run;
    run = Dp[base * 64 + j] * run + Sl[base * 8192 + kv];
  }
}

__global__ __launch_bounds__(128) void wkv_pass3(
    const float* __restrict__ r, const float* __restrict__ k,
    const float* __restrict__ ew, const float* __restrict__ v,
    const float* __restrict__ rbk, const float* __restrict__ Ss,
    float* __restrict__ o)
{
  __shared__ float rL[CH_][64], kL[CH_][64], eL[CH_][64], vL[CH_][128], rbL[CH_];
  int blk = blockIdx.x;
  int c = blk & (NC_ - 1), bh = blk >> 5;
  int b = bh >> 2, hh = bh & 3;
  int tid = threadIdx.x;
  size_t tbase = (size_t)b * T_ + (size_t)c * CH_;
  for (int idx = tid; idx < CH_ * 64; idx += 128) {
    int s = idx >> 6, j = idx & 63;
    size_t g = (tbase + s) * 256 + hh * 64 + j;
    rL[s][j] = r[g]; kL[s][j] = k[g]; eL[s][j] = ew[g];
  }
  for (int idx = tid; idx < CH_ * 128; idx += 128) {
    int s = idx >> 7, vi = idx & 127;
    vL[s][vi] = v[(tbase + s) * 512 + hh * 128 + vi];
  }
  if (tid < CH_) rbL[tid] = rbk[(tbase + tid) * 4 + hh];
  __syncthreads();
  float S[64];
  size_t sbase = (size_t)blk * 8192;
#pragma unroll
  for (int j = 0; j < 64; j++) S[j] = Ss[sbase + j * 128 + tid];
  for (int s = 0; s < CH_; s++) {
    float vv = vL[s][tid];
    float oa = rbL[s] * vv;
    const float4* r4p = (const float4*)&rL[s][0];
    const float4* e4p = (const float4*)&eL[s][0];
    const float4* k4p = (const float4*)&kL[s][0];
#pragma unroll
    for (int q = 0; q < 16; q++) {
      float4 r4 = r4p[q], e4 = e4p[q], k4 = k4p[q];
      oa += r4.x * S[4 * q + 0] + r4.y * S[4 * q + 1]
          + r4.z * S[4 * q + 2] + r4.w * S[4 * q + 3];
      S[4 * q + 0] = e4.x * S[4 * q + 0] + k4.x * vv;
      S[4 * q + 1] = e4.y * S[4 * q + 1] + k4.y * vv;
      S[4 * q + 2] = e4.z * S[4 * q + 2] + k4.z * vv;
      S[4 * q + 3] = e4.w * S[4 * q + 3] + k4.w * vv;
    }
    o[(tbase + s) * 512 + hh * 128 + tid] = oa;
  }
}

// --------------------------- groupnorm + swish gate -------------------------
__global__ __launch_bounds__(256) void gn_gate_kernel(
    float* __restrict__ o, const float* __restrict__ g,
    const float* __restrict__ gg, const float* __restrict__ gb)
{
  __shared__ float ov[512], ps[64], qs[64], mh[4], vh[4];
  int t = blockIdx.x, tid = threadIdx.x;
  size_t base = (size_t)t * 512;
  ov[tid] = o[base + tid]; ov[tid + 256] = o[base + 256 + tid];
  __syncthreads();
  if (tid < 64) {
    int hh = tid >> 4, sg = tid & 15;
    const float* p = &ov[hh * 128 + sg * 8];
    float s = 0.f, q = 0.f;
    for (int i = 0; i < 8; i++) { s += p[i]; q += p[i] * p[i]; }
    ps[tid] = s; qs[tid] = q;
  }
  __syncthreads();
  if (tid < 4) {
    float s = 0.f, q = 0.f;
    for (int i = 0; i < 16; i++) { s += ps[tid * 16 + i]; q += qs[tid * 16 + i]; }
    float m = s * (1.f / 128.f);
    mh[tid] = m; vh[tid] = q * (1.f / 128.f) - m * m;
  }
  __syncthreads();
  for (int c = tid; c < 512; c += 256) {
    int hh = c >> 7;
    float nrm = (ov[c] - mh[hh]) * rsqrtf(vh[hh] + EPS_);
    float gv = g[base + c];
    float sw = gv * (1.f / (1.f + expf(-gv)));
    o[base + c] = (nrm * gg[c] + gb[c]) * sw;
  }
}

// --------------------------- FFN token-shift mix ----------------------------
__global__ __launch_bounds__(256) void ffnmix_kernel(
    const float* __restrict__ hf, const float* __restrict__ fkmu,
    const float* __restrict__ frmu,
    float* __restrict__ mfk, float* __restrict__ mfr)
{
  int t = blockIdx.x, tid = threadIdx.x, tt = t & (T_ - 1);
  size_t base = (size_t)t * 512;
  for (int c = tid; c < 512; c += 256) {
    float cur  = hf[base + c];
    float prev = tt ? hf[base - 512 + c] : 0.f;
    float d = prev - cur;
    mfk[base + c] = cur + d * fkmu[c];
    mfr[base + c] = cur + d * frmu[c];
  }
}

// ---------------------------------------------------------------------------
extern "C" void kernel_launch(void* const* d_in, const int* in_sizes, int n_in,
                              void* d_out, int out_size, void* d_ws, size_t ws_size,
                              hipStream_t stream) {
  (void)in_sizes; (void)n_in; (void)out_size; (void)ws_size;
  const float* x        = (const float*)d_in[0];
  const float* pre_g    = (const float*)d_in[1];
  const float* pre_b    = (const float*)d_in[2];
  const float* attn_g   = (const float*)d_in[3];
  const float* attn_b   = (const float*)d_in[4];
  const float* ffn_g    = (const float*)d_in[5];
  const float* ffn_b    = (const float*)d_in[6];
  const float* xproj_mu = (const float*)d_in[7];
  const float* xproj_w1 = (const float*)d_in[8];
  const float* xproj_w2 = (const float*)d_in[9];
  const float* x_bias   = (const float*)d_in[10];
  const float* r_W      = (const float*)d_in[11];
  const float* w_W1     = (const float*)d_in[12];
  const float* w_W2     = (const float*)d_in[13];
  const float* w_b      = (const float*)d_in[14];
  const float* k_W      = (const float*)d_in[15];
  const float* v_W      = (const float*)d_in[16];
  const float* g_W      = (const float*)d_in[17];
  const float* bonus    = (const float*)d_in[18];
  const float* gnorm_g  = (const float*)d_in[19];
  const float* gnorm_b  = (const float*)d_in[20];
  const float* o_W      = (const float*)d_in[21];
  const float* fk_mu    = (const float*)d_in[22];
  const float* fk_W     = (const float*)d_in[23];
  const float* fv_W     = (const float*)d_in[24];
  const float* fr_mu    = (const float*)d_in[25];
  const float* fr_W     = (const float*)d_in[26];

  const size_t BTH = (size_t)BT_ * 512;  // 4,194,304
  size_t cur = 0;
  auto alloc = [&](size_t nf) { float* p = (float*)((char*)d_ws + cur); cur += nf * 4; return p; };
  float* x0   = alloc(BTH);
  float* hbuf = alloc(BTH);
  float* m5   = alloc(5 * BTH);          // slots: m_r,m_w,m_k,m_v,m_g
  float* rbuf = alloc((size_t)BT_ * 256);
  float* kbuf = alloc((size_t)BT_ * 256);
  float* ebuf = alloc((size_t)BT_ * 256);
  float* vbuf = alloc(BTH);
  float* gbuf = alloc(BTH);
  float* wtmp = alloc((size_t)BT_ * 64);
  float* rbk  = alloc((size_t)BT_ * 4);
  float* Sl   = alloc((size_t)32 * 32 * 8192);
  float* Ss   = alloc((size_t)32 * 32 * 8192);
  float* Dp   = alloc((size_t)32 * 32 * 64);
  // reuse (all original occupants dead by time of write):
  float* obuf = m5;                      // slot0 (m_r)
  float* res  = m5 + BTH;                // slot1 (m_w)
  float* hf   = m5 + 2 * BTH;            // slot2 (m_k)
  float* mfk  = m5 + 3 * BTH;            // slot3 (m_v)
  float* mfr  = m5 + 4 * BTH;            // slot4 (m_g)
  float* kkb  = Sl;                      // 8192x1024 f32
  float* valb = Ss;                      // 8192x512 f32
  // xproj scratch (aliases buffers dead during xproj phase):
  float* ybuf  = rbuf;                   // 16MB: rbuf+kbuf region (8192x512)
  float* dlbuf = vbuf;                   // 16MB (8192x512)
  float* z5buf = gbuf;                   // 6.3MB of gbuf (8192x192)
  float* w1p   = wtmp;                   // 0.4MB of wtmp (192x512)

  ln2_kernel<<<BT_, 256, 0, stream>>>(x, pre_g, pre_b, attn_g, attn_b, x0, hbuf);

  // ---- xproj as GEMMs ----
  ymix_kernel<<<BT_, 256, 0, stream>>>(hbuf, xproj_mu, ybuf, dlbuf);
  w1pad_kernel<<<(192 * 512) / 256, 256, 0, stream>>>(xproj_w1, w1p);
  sgemm_nt<EPI_TANH><<<dim3(128, 3), 256, 0, stream>>>(
      ybuf, w1p, z5buf, BT_, 192, 512, 512, 512, 192, nullptr, nullptr, nullptr);
  for (int n = 0; n < 5; n++) {
    sgemm_nt<EPI_XMIX><<<dim3(128, 8), 256, 0, stream>>>(
        z5buf + n * 32, xproj_w2 + n * 32, m5 + (size_t)n * BTH,
        BT_, 512, 32, 192, 160, 512, x_bias + n * 512, hbuf, dlbuf);
  }

  sgemm_nt<EPI_NONE><<<dim3(128, 4), 256, 0, stream>>>(m5 + 0 * BTH, r_W, rbuf, BT_, 256, 512, 512, 512, 256, nullptr, nullptr, nullptr);
  sgemm_nt<EPI_TANH><<<dim3(128, 1), 256, 0, stream>>>(m5 + 1 * BTH, w_W1, wtmp, BT_, 64, 512, 512, 512, 64, nullptr, nullptr, nullptr);
  sgemm_nt<EPI_EXPEXP><<<dim3(128, 4), 256, 0, stream>>>(wtmp, w_W2, ebuf, BT_, 256, 64, 64, 64, 256, w_b, nullptr, nullptr);
  sgemm_nt<EPI_NONE><<<dim3(128, 4), 256, 0, stream>>>(m5 + 2 * BTH, k_W, kbuf, BT_, 256, 512, 512, 512, 256, nullptr, nullptr, nullptr);
  sgemm_nt<EPI_NONE><<<dim3(128, 8), 256, 0, stream>>>(m5 + 3 * BTH, v_W, vbuf, BT_, 512, 512, 512, 512, 512, nullptr, nullptr, nullptr);
  sgemm_nt<EPI_NONE><<<dim3(128, 8), 256, 0, stream>>>(m5 + 4 * BTH, g_W, gbuf, BT_, 512, 512, 512, 512, 512, nullptr, nullptr, nullptr);

  rbk_kernel<<<BT_, 256, 0, stream>>>(rbuf, kbuf, bonus, rbk);
  wkv_pass1<<<1024, 128, 0, stream>>>(kbuf, ebuf, vbuf, Sl, Dp);
  wkv_scan<<<1024, 256, 0, stream>>>(Sl, Dp, Ss);
  wkv_pass3<<<1024, 128, 0, stream>>>(rbuf, kbuf, ebuf, vbuf, rbk, Ss, obuf);

  gn_gate_kernel<<<BT_, 256, 0, stream>>>(obuf, gbuf, gnorm_g, gnorm_b);
  sgemm_nt<EPI_RES><<<dim3(128, 8), 256, 0, stream>>>(obuf, o_W, res, BT_, 512, 512, 512, 512, 512, nullptr, x0, nullptr);

  ln1_kernel<<<BT_, 256, 0, stream>>>(res, ffn_g, ffn_b, hf);
  ffnmix_kernel<<<BT_, 256, 0, stream>>>(hf, fk_mu, fr_mu, mfk, mfr);
  sgemm_nt<EPI_RELU2><<<dim3(128, 16), 256, 0, stream>>>(mfk, fk_W, kkb, BT_, 1024, 512, 512, 512, 1024, nullptr, nullptr, nullptr);
  sgemm_nt<EPI_NONE><<<dim3(128, 8), 256, 0, stream>>>(kkb, fv_W, valb, BT_, 512, 1024, 1024, 1024, 512, nullptr, nullptr, nullptr);
  sgemm_nt<EPI_OUT><<<dim3(128, 8), 256, 0, stream>>>(mfr, fr_W, (float*)d_out, BT_, 512, 512, 512, 512, 512, nullptr, res, valb);
}

// Round 4
// 592.726 us; speedup vs baseline: 2.2930x; 1.5164x over previous
//
#include <hip/hip_runtime.h>

// ---------------------------------------------------------------------------
// RWKV6 layer forward, MI355X. Round 3: all GEMMs moved to bf16 MFMA
// (16x16x32), fp32 accumulate, fp32 epilogues. fp32->bf16 RNE conversion
// happens during LDS staging; LDS uses subtiled [kgrp][frag][row][8] layout.
// ---------------------------------------------------------------------------

#define DEVINL __device__ __forceinline__

constexpr int B_  = 8, T_ = 1024, NH_ = 4;
constexpr int BT_ = B_ * T_;          // 8192 tokens
constexpr float EPS_ = 1e-5f;
constexpr int CH_ = 32;               // WKV chunk length
constexpr int NC_ = T_ / CH_;         // 32 chunks per sequence

typedef __bf16 bf16x8 __attribute__((ext_vector_type(8)));
typedef float  f32x4  __attribute__((ext_vector_type(4)));

DEVINL short f2bs(float f) {          // fp32 -> bf16 bits, round-nearest-even
  union { float f; unsigned int i; } c; c.f = f;
  unsigned int x = c.i;
  return (short)((x + 0x7fffu + ((x >> 16) & 1u)) >> 16);
}

// block-wide sum over 256 threads (4 waves), result broadcast to all threads
DEVINL float block_sum256(float v, float* sb) {
  for (int o = 32; o; o >>= 1) v += __shfl_down(v, o);
  int w = threadIdx.x >> 6;
  __syncthreads();
  if ((threadIdx.x & 63) == 0) sb[w] = v;
  __syncthreads();
  return sb[0] + sb[1] + sb[2] + sb[3];
}

// --------------------------- LN kernels ------------------------------------
__global__ __launch_bounds__(256) void ln2_kernel(
    const float* __restrict__ x,
    const float* __restrict__ pg, const float* __restrict__ pb,
    const float* __restrict__ ag, const float* __restrict__ ab,
    float* __restrict__ x0, float* __restrict__ h)
{
  __shared__ float sb[4];
  size_t base = (size_t)blockIdx.x * 512;
  int tid = threadIdx.x;
  float v0 = x[base + tid], v1 = x[base + 256 + tid];
  float m = block_sum256(v0 + v1, sb) * (1.f / 512.f);
  float d0 = v0 - m, d1 = v1 - m;
  float var = block_sum256(d0 * d0 + d1 * d1, sb) * (1.f / 512.f);
  float rs = rsqrtf(var + EPS_);
  float a0 = d0 * rs * pg[tid]       + pb[tid];
  float a1 = d1 * rs * pg[tid + 256] + pb[tid + 256];
  x0[base + tid] = a0; x0[base + 256 + tid] = a1;
  float m2 = block_sum256(a0 + a1, sb) * (1.f / 512.f);
  float e0 = a0 - m2, e1 = a1 - m2;
  float var2 = block_sum256(e0 * e0 + e1 * e1, sb) * (1.f / 512.f);
  float rs2 = rsqrtf(var2 + EPS_);
  h[base + tid]       = e0 * rs2 * ag[tid]       + ab[tid];
  h[base + 256 + tid] = e1 * rs2 * ag[tid + 256] + ab[tid + 256];
}

__global__ __launch_bounds__(256) void ln1_kernel(
    const float* __restrict__ in,
    const float* __restrict__ g, const float* __restrict__ b,
    float* __restrict__ out)
{
  __shared__ float sb[4];
  size_t base = (size_t)blockIdx.x * 512;
  int tid = threadIdx.x;
  float v0 = in[base + tid], v1 = in[base + 256 + tid];
  float m = block_sum256(v0 + v1, sb) * (1.f / 512.f);
  float d0 = v0 - m, d1 = v1 - m;
  float var = block_sum256(d0 * d0 + d1 * d1, sb) * (1.f / 512.f);
  float rs = rsqrtf(var + EPS_);
  out[base + tid]       = d0 * rs * g[tid]       + b[tid];
  out[base + 256 + tid] = d1 * rs * g[tid + 256] + b[tid + 256];
}

// --------------------------- xproj helpers ----------------------------------
__global__ __launch_bounds__(256) void ymix_kernel(
    const float* __restrict__ h, const float* __restrict__ mu,
    float* __restrict__ y, float* __restrict__ dl)
{
  int t = blockIdx.x, tid = threadIdx.x, tt = t & (T_ - 1);
  size_t base = (size_t)t * 512;
  for (int c = tid; c < 512; c += 256) {
    float cur  = h[base + c];
    float prev = tt ? h[base - 512 + c] : 0.f;
    float d = prev - cur;
    dl[base + c] = d;
    y[base + c] = cur + d * mu[c];
  }
}

__global__ __launch_bounds__(256) void w1pad_kernel(
    const float* __restrict__ W1, float* __restrict__ W1p)
{
  int i = blockIdx.x * 256 + threadIdx.x;   // < 192*512
  int r = i >> 9;
  W1p[i] = (r < 160) ? W1[i] : 0.f;
}

// --------------------------- MFMA GEMM -------------------------------------
// C[M,N] = epi(A[M,K] @ W[N,K]^T). A,W fp32 row-major (strides lda/ldw),
// converted to bf16 during LDS staging. BM=128, BN in {64,128}, BK=32.
// 256 threads = 4 waves, 2x2 wave grid; per-wave 64 x (BN/2) output.
// Fragment layout (m89-verified): A/B lane l -> row l&15, k 8*(l>>4)+j;
// C/D lane l -> col l&15, row (l>>4)*4+reg.
enum { EPI_NONE = 0, EPI_TANH = 1, EPI_EXPEXP = 2, EPI_RES = 3, EPI_RELU2 = 4,
       EPI_OUT = 5, EPI_XMIX = 6 };

template <int EPI, int BN>
__global__ __launch_bounds__(256) void mgemm(
    const float* __restrict__ A, const float* __restrict__ W,
    float* __restrict__ C, int M, int N, int K,
    int lda, int ldw, int ldc,
    const float* __restrict__ bias,
    const float* __restrict__ aux1, const float* __restrict__ aux2)
{
  constexpr int NFR = BN / 32;               // n-fragments per wave
  __shared__ short As[4][8][16][8];          // [kgrp][mfrag][row][j]
  __shared__ short Ws[4][BN / 16][16][8];
  int m0 = blockIdx.x * 128, n0 = blockIdx.y * BN;
  int tid = threadIdx.x;
  int lane = tid & 63, wid = tid >> 6;
  int wm = wid >> 1, wn = wid & 1;
  int lrow = lane & 15, lkg = lane >> 4;

  // staging coords
  int ar = tid >> 1, akh = (tid & 1) * 16;           // A: 16 floats/thread
  const float* aptr = A + (size_t)(m0 + ar) * lda + akh;
  const float* wptr;
  int wr, wkq;
  if constexpr (BN == 128) {
    wr = tid >> 1; wkq = (tid & 1) * 16;
    wptr = W + (size_t)(n0 + wr) * ldw + wkq;
  } else {
    wr = tid >> 2; wkq = (tid & 3) * 8;
    wptr = W + (size_t)(n0 + wr) * ldw + wkq;
  }

  f32x4 acc[4][NFR];
#pragma unroll
  for (int mf = 0; mf < 4; mf++)
#pragma unroll
    for (int nf = 0; nf < NFR; nf++) acc[mf][nf] = (f32x4){0.f, 0.f, 0.f, 0.f};

  for (int kb = 0; kb < K; kb += 32) {
    float4 a0 = *(const float4*)(aptr + kb);
    float4 a1 = *(const float4*)(aptr + kb + 4);
    float4 a2 = *(const float4*)(aptr + kb + 8);
    float4 a3 = *(const float4*)(aptr + kb + 12);
    float4 w0 = *(const float4*)(wptr + kb);
    float4 w1 = *(const float4*)(wptr + kb + 4);
    float4 w2, w3;
    if constexpr (BN == 128) {
      w2 = *(const float4*)(wptr + kb + 8);
      w3 = *(const float4*)(wptr + kb + 12);
    }
    __syncthreads();                        // protect previous iter's reads
    {
      union { short s[8]; int4 v; } p0, p1;
      const float* af = (const float*)&a0;
      p0.s[0]=f2bs(af[0]); p0.s[1]=f2bs(af[1]); p0.s[2]=f2bs(af[2]); p0.s[3]=f2bs(af[3]);
      af = (const float*)&a1;
      p0.s[4]=f2bs(af[0]); p0.s[5]=f2bs(af[1]); p0.s[6]=f2bs(af[2]); p0.s[7]=f2bs(af[3]);
      af = (const float*)&a2;
      p1.s[0]=f2bs(af[0]); p1.s[1]=f2bs(af[1]); p1.s[2]=f2bs(af[2]); p1.s[3]=f2bs(af[3]);
      af = (const float*)&a3;
      p1.s[4]=f2bs(af[0]); p1.s[5]=f2bs(af[1]); p1.s[6]=f2bs(af[2]); p1.s[7]=f2bs(af[3]);
      int kg = akh >> 3;                    // 0 or 2
      *(int4*)&As[kg][ar >> 4][ar & 15][0]     = p0.v;
      *(int4*)&As[kg + 1][ar >> 4][ar & 15][0] = p1.v;
    }
    if constexpr (BN == 128) {
      union { short s[8]; int4 v; } q0, q1;
      const float* wf = (const float*)&w0;
      q0.s[0]=f2bs(wf[0]); q0.s[1]=f2bs(wf[1]); q0.s[2]=f2bs(wf[2]); q0.s[3]=f2bs(wf[3]);
      wf = (const float*)&w1;
      q0.s[4]=f2bs(wf[0]); q0.s[5]=f2bs(wf[1]); q0.s[6]=f2bs(wf[2]); q0.s[7]=f2bs(wf[3]);
      wf = (const float*)&w2;
      q1.s[0]=f2bs(wf[0]); q1.s[1]=f2bs(wf[1]); q1.s[2]=f2bs(wf[2]); q1.s[3]=f2bs(wf[3]);
      wf = (const float*)&w3;
      q1.s[4]=f2bs(wf[0]); q1.s[5]=f2bs(wf[1]); q1.s[6]=f2bs(wf[2]); q1.s[7]=f2bs(wf[3]);
      int kg = wkq >> 3;
      *(int4*)&Ws[kg][wr >> 4][wr & 15][0]     = q0.v;
      *(int4*)&Ws[kg + 1][wr >> 4][wr & 15][0] = q1.v;
    } else {
      union { short s[8]; int4 v; } q0;
      const float* wf = (const float*)&w0;
      q0.s[0]=f2bs(wf[0]); q0.s[1]=f2bs(wf[1]); q0.s[2]=f2bs(wf[2]); q0.s[3]=f2bs(wf[3]);
      wf = (const float*)&w1;
      q0.s[4]=f2bs(wf[0]); q0.s[5]=f2bs(wf[1]); q0.s[6]=f2bs(wf[2]); q0.s[7]=f2bs(wf[3]);
      *(int4*)&Ws[wkq >> 3][wr >> 4][wr & 15][0] = q0.v;
    }
    __syncthreads();

    bf16x8 bfrag[NFR];
#pragma unroll
    for (int nf = 0; nf < NFR; nf++)
      bfrag[nf] = *(const bf16x8*)&Ws[lkg][wn * NFR + nf][lrow][0];
#pragma unroll
    for (int mf = 0; mf < 4; mf++) {
      bf16x8 afrag = *(const bf16x8*)&As[lkg][wm * 4 + mf][lrow][0];
#pragma unroll
      for (int nf = 0; nf < NFR; nf++)
        acc[mf][nf] = __builtin_amdgcn_mfma_f32_16x16x32_bf16(
            afrag, bfrag[nf], acc[mf][nf], 0, 0, 0);
    }
  }

  // epilogue
#pragma unroll
  for (int mf = 0; mf < 4; mf++) {
#pragma unroll
    for (int nf = 0; nf < NFR; nf++) {
#pragma unroll
      for (int r = 0; r < 4; r++) {
        int m = m0 + wm * 64 + mf * 16 + (lane >> 4) * 4 + r;
        int n = n0 + wn * (NFR * 16) + nf * 16 + lrow;
        size_t off = (size_t)m * ldc + n;
        float c = acc[mf][nf][r];
        if constexpr (EPI == EPI_TANH) {
          c = tanhf(c);
        } else if constexpr (EPI == EPI_EXPEXP) {
          c = expf(-expf(c + bias[n]));
        } else if constexpr (EPI == EPI_RES) {
          c += aux1[off];
        } else if constexpr (EPI == EPI_RELU2) {
          c = fmaxf(c, 0.f); c *= c;
        } else if constexpr (EPI == EPI_OUT) {
          c = aux1[off] + aux2[off] * (1.f / (1.f + expf(-c)));
        } else if constexpr (EPI == EPI_XMIX) {
          c = aux1[off] + aux2[off] * (c + bias[n]);
        }
        C[off] = c;
      }
    }
  }
}

// --------------------------- bonus scalar ----------------------------------
__global__ __launch_bounds__(256) void rbk_kernel(
    const float* __restrict__ r, const float* __restrict__ k,
    const float* __restrict__ bonus, float* __restrict__ rbk)
{
  int t = blockIdx.x, tid = threadIdx.x;
  int hh = tid >> 6, j = tid & 63;
  size_t g = (size_t)t * 256 + hh * 64 + j;
  float p = r[g] * k[g] * bonus[hh * 64 + j];
  for (int o = 32; o; o >>= 1) p += __shfl_down(p, o);
  if (j == 0) rbk[(size_t)t * 4 + hh] = p;
}

// --------------------------- WKV 3-pass chunked scan ------------------------
__global__ __launch_bounds__(128) void wkv_pass1(
    const float* __restrict__ k, const float* __restrict__ ew,
    const float* __restrict__ v, float* __restrict__ Sl, float* __restrict__ Dp)
{
  __shared__ float kL[CH_][64], eL[CH_][64], vL[CH_][128];
  int blk = blockIdx.x;
  int c = blk & (NC_ - 1), bh = blk >> 5;
  int b = bh >> 2, hh = bh & 3;
  int tid = threadIdx.x;
  size_t tbase = (size_t)b * T_ + (size_t)c * CH_;
  for (int idx = tid; idx < CH_ * 64; idx += 128) {
    int s = idx >> 6, j = idx & 63;
    size_t g = (tbase + s) * 256 + hh * 64 + j;
    kL[s][j] = k[g]; eL[s][j] = ew[g];
  }
  for (int idx = tid; idx < CH_ * 128; idx += 128) {
    int s = idx >> 7, vi = idx & 127;
    vL[s][vi] = v[(tbase + s) * 512 + hh * 128 + vi];
  }
  __syncthreads();
  float S[64];
#pragma unroll
  for (int j = 0; j < 64; j++) S[j] = 0.f;
  for (int s = 0; s < CH_; s++) {
    float vv = vL[s][tid];
    const float4* e4p = (const float4*)&eL[s][0];
    const float4* k4p = (const float4*)&kL[s][0];
#pragma unroll
    for (int q = 0; q < 16; q++) {
      float4 e4 = e4p[q], k4 = k4p[q];
      S[4 * q + 0] = e4.x * S[4 * q + 0] + k4.x * vv;
      S[4 * q + 1] = e4.y * S[4 * q + 1] + k4.y * vv;
      S[4 * q + 2] = e4.z * S[4 * q + 2] + k4.z * vv;
      S[4 * q + 3] = e4.w * S[4 * q + 3] + k4.w * vv;
    }
  }
  size_t sbase = (size_t)blk * 8192;
#pragma unroll
  for (int j = 0; j < 64; j++) Sl[sbase + j * 128 + tid] = S[j];
  if (tid < 64) {
    float d = 1.f;
    for (int s = 0; s < CH_; s++) d *= eL[s][tid];
    Dp[(size_t)blk * 64 + tid] = d;
  }
}

__global__ __launch_bounds__(256) void wkv_scan(
    const float* __restrict__ Sl, const float* __restrict__ Dp, float* __restrict__ Ss)
{
  int e = blockIdx.x * 256 + threadIdx.x;   // < 32*8192
  int bh = e >> 13; int kv = e & 8191; int j = kv >> 7;
  float run = 0.f;
  for (int c = 0; c < NC_; c++) {
    size_t base = (size_t)bh * NC_ + c;
    Ss[base * 8192 + kv] = run;
    run = Dp[base * 64 + j] * run + Sl[base * 8192 + kv];
  }
}

__global__ __launch_bounds__(128) void wkv_pass3(
    const float* __restrict__ r, const float* __restrict__ k,
    const float* __restrict__ ew, const float* __restrict__ v,
    const float* __restrict__ rbk, const float* __restrict__ Ss,
    float* __restrict__ o)
{
  __shared__ float rL[CH_][64], kL[CH_][64], eL[CH_][64], vL[CH_][128], rbL[CH_];
  int blk = blockIdx.x;
  int c = blk & (NC_ - 1), bh = blk >> 5;
  int b = bh >> 2, hh = bh & 3;
  int tid = threadIdx.x;
  size_t tbase = (size_t)b * T_ + (size_t)c * CH_;
  for (int idx = tid; idx < CH_ * 64; idx += 128) {
    int s = idx >> 6, j = idx & 63;
    size_t g = (tbase + s) * 256 + hh * 64 + j;
    rL[s][j] = r[g]; kL[s][j] = k[g]; eL[s][j] = ew[g];
  }
  for (int idx = tid; idx < CH_ * 128; idx += 128) {
    int s = idx >> 7, vi = idx & 127;
    vL[s][vi] = v[(tbase + s) * 512 + hh * 128 + vi];
  }
  if (tid < CH_) rbL[tid] = rbk[(tbase + tid) * 4 + hh];
  __syncthreads();
  float S[64];
  size_t sbase = (size_t)blk * 8192;
#pragma unroll
  for (int j = 0; j < 64; j++) S[j] = Ss[sbase + j * 128 + tid];
  for (int s = 0; s < CH_; s++) {
    float vv = vL[s][tid];
    float oa = rbL[s] * vv;
    const float4* r4p = (const float4*)&rL[s][0];
    const float4* e4p = (const float4*)&eL[s][0];
    const float4* k4p = (const float4*)&kL[s][0];
#pragma unroll
    for (int q = 0; q < 16; q++) {
      float4 r4 = r4p[q], e4 = e4p[q], k4 = k4p[q];
      oa += r4.x * S[4 * q + 0] + r4.y * S[4 * q + 1]
          + r4.z * S[4 * q + 2] + r4.w * S[4 * q + 3];
      S[4 * q + 0] = e4.x * S[4 * q + 0] + k4.x * vv;
      S[4 * q + 1] = e4.y * S[4 * q + 1] + k4.y * vv;
      S[4 * q + 2] = e4.z * S[4 * q + 2] + k4.z * vv;
      S[4 * q + 3] = e4.w * S[4 * q + 3] + k4.w * vv;
    }
    o[(tbase + s) * 512 + hh * 128 + tid] = oa;
  }
}

// --------------------------- groupnorm + swish gate -------------------------
__global__ __launch_bounds__(256) void gn_gate_kernel(
    float* __restrict__ o, const float* __restrict__ g,
    const float* __restrict__ gg, const float* __restrict__ gb)
{
  __shared__ float ov[512], ps[64], qs[64], mh[4], vh[4];
  int t = blockIdx.x, tid = threadIdx.x;
  size_t base = (size_t)t * 512;
  ov[tid] = o[base + tid]; ov[tid + 256] = o[base + 256 + tid];
  __syncthreads();
  if (tid < 64) {
    int hh = tid >> 4, sg = tid & 15;
    const float* p = &ov[hh * 128 + sg * 8];
    float s = 0.f, q = 0.f;
    for (int i = 0; i < 8; i++) { s += p[i]; q += p[i] * p[i]; }
    ps[tid] = s; qs[tid] = q;
  }
  __syncthreads();
  if (tid < 4) {
    float s = 0.f, q = 0.f;
    for (int i = 0; i < 16; i++) { s += ps[tid * 16 + i]; q += qs[tid * 16 + i]; }
    float m = s * (1.f / 128.f);
    mh[tid] = m; vh[tid] = q * (1.f / 128.f) - m * m;
  }
  __syncthreads();
  for (int c = tid; c < 512; c += 256) {
    int hh = c >> 7;
    float nrm = (ov[c] - mh[hh]) * rsqrtf(vh[hh] + EPS_);
    float gv = g[base + c];
    float sw = gv * (1.f / (1.f + expf(-gv)));
    o[base + c] = (nrm * gg[c] + gb[c]) * sw;
  }
}

// --------------------------- FFN token-shift mix ----------------------------
__global__ __launch_bounds__(256) void ffnmix_kernel(
    const float* __restrict__ hf, const float* __restrict__ fkmu,
    const float* __restrict__ frmu,
    float* __restrict__ mfk, float* __restrict__ mfr)
{
  int t = blockIdx.x, tid = threadIdx.x, tt = t & (T_ - 1);
  size_t base = (size_t)t * 512;
  for (int c = tid; c < 512; c += 256) {
    float cur  = hf[base + c];
    float prev = tt ? hf[base - 512 + c] : 0.f;
    float d = prev - cur;
    mfk[base + c] = cur + d * fkmu[c];
    mfr[base + c] = cur + d * frmu[c];
  }
}

// ---------------------------------------------------------------------------
extern "C" void kernel_launch(void* const* d_in, const int* in_sizes, int n_in,
                              void* d_out, int out_size, void* d_ws, size_t ws_size,
                              hipStream_t stream) {
  (void)in_sizes; (void)n_in; (void)out_size; (void)ws_size;
  const float* x        = (const float*)d_in[0];
  const float* pre_g    = (const float*)d_in[1];
  const float* pre_b    = (const float*)d_in[2];
  const float* attn_g   = (const float*)d_in[3];
  const float* attn_b   = (const float*)d_in[4];
  const float* ffn_g    = (const float*)d_in[5];
  const float* ffn_b    = (const float*)d_in[6];
  const float* xproj_mu = (const float*)d_in[7];
  const float* xproj_w1 = (const float*)d_in[8];
  const float* xproj_w2 = (const float*)d_in[9];
  const float* x_bias   = (const float*)d_in[10];
  const float* r_W      = (const float*)d_in[11];
  const float* w_W1     = (const float*)d_in[12];
  const float* w_W2     = (const float*)d_in[13];
  const float* w_b      = (const float*)d_in[14];
  const float* k_W      = (const float*)d_in[15];
  const float* v_W      = (const float*)d_in[16];
  const float* g_W      = (const float*)d_in[17];
  const float* bonus    = (const float*)d_in[18];
  const float* gnorm_g  = (const float*)d_in[19];
  const float* gnorm_b  = (const float*)d_in[20];
  const float* o_W      = (const float*)d_in[21];
  const float* fk_mu    = (const float*)d_in[22];
  const float* fk_W     = (const float*)d_in[23];
  const float* fv_W     = (const float*)d_in[24];
  const float* fr_mu    = (const float*)d_in[25];
  const float* fr_W     = (const float*)d_in[26];

  const size_t BTH = (size_t)BT_ * 512;  // 4,194,304
  size_t cur = 0;
  auto alloc = [&](size_t nf) { float* p = (float*)((char*)d_ws + cur); cur += nf * 4; return p; };
  float* x0   = alloc(BTH);
  float* hbuf = alloc(BTH);
  float* m5   = alloc(5 * BTH);          // slots: m_r,m_w,m_k,m_v,m_g
  float* rbuf = alloc((size_t)BT_ * 256);
  float* kbuf = alloc((size_t)BT_ * 256);
  float* ebuf = alloc((size_t)BT_ * 256);
  float* vbuf = alloc(BTH);
  float* gbuf = alloc(BTH);
  float* wtmp = alloc((size_t)BT_ * 64);
  float* rbk  = alloc((size_t)BT_ * 4);
  float* Sl   = alloc((size_t)32 * 32 * 8192);
  float* Ss   = alloc((size_t)32 * 32 * 8192);
  float* Dp   = alloc((size_t)32 * 32 * 64);
  // reuse (all original occupants dead by time of write):
  float* obuf = m5;                      // slot0 (m_r)
  float* res  = m5 + BTH;                // slot1 (m_w)
  float* hf   = m5 + 2 * BTH;            // slot2 (m_k)
  float* mfk  = m5 + 3 * BTH;            // slot3 (m_v)
  float* mfr  = m5 + 4 * BTH;            // slot4 (m_g)
  float* kkb  = Sl;                      // 8192x1024 f32
  float* valb = Ss;                      // 8192x512 f32
  // xproj scratch (aliases buffers dead during xproj phase):
  float* ybuf  = rbuf;                   // 8192x512 (rbuf+kbuf region)
  float* dlbuf = vbuf;                   // 8192x512
  float* z5buf = gbuf;                   // 8192x192
  float* w1p   = wtmp;                   // 192x512

  ln2_kernel<<<BT_, 256, 0, stream>>>(x, pre_g, pre_b, attn_g, attn_b, x0, hbuf);

  // ---- xproj as GEMMs ----
  ymix_kernel<<<BT_, 256, 0, stream>>>(hbuf, xproj_mu, ybuf, dlbuf);
  w1pad_kernel<<<(192 * 512) / 256, 256, 0, stream>>>(xproj_w1, w1p);
  mgemm<EPI_TANH, 64><<<dim3(64, 3), 256, 0, stream>>>(
      ybuf, w1p, z5buf, BT_, 192, 512, 512, 512, 192, nullptr, nullptr, nullptr);
  for (int n = 0; n < 5; n++) {
    mgemm<EPI_XMIX, 128><<<dim3(64, 4), 256, 0, stream>>>(
        z5buf + n * 32, xproj_w2 + n * 32, m5 + (size_t)n * BTH,
        BT_, 512, 32, 192, 160, 512, x_bias + n * 512, hbuf, dlbuf);
  }

  mgemm<EPI_NONE, 128><<<dim3(64, 2), 256, 0, stream>>>(m5 + 0 * BTH, r_W, rbuf, BT_, 256, 512, 512, 512, 256, nullptr, nullptr, nullptr);
  mgemm<EPI_TANH, 64><<<dim3(64, 1), 256, 0, stream>>>(m5 + 1 * BTH, w_W1, wtmp, BT_, 64, 512, 512, 512, 64, nullptr, nullptr, nullptr);
  mgemm<EPI_EXPEXP, 128><<<dim3(64, 2), 256, 0, stream>>>(wtmp, w_W2, ebuf, BT_, 256, 64, 64, 64, 256, w_b, nullptr, nullptr);
  mgemm<EPI_NONE, 128><<<dim3(64, 2), 256, 0, stream>>>(m5 + 2 * BTH, k_W, kbuf, BT_, 256, 512, 512, 512, 256, nullptr, nullptr, nullptr);
  mgemm<EPI_NONE, 128><<<dim3(64, 4), 256, 0, stream>>>(m5 + 3 * BTH, v_W, vbuf, BT_, 512, 512, 512, 512, 512, nullptr, nullptr, nullptr);
  mgemm<EPI_NONE, 128><<<dim3(64, 4), 256, 0, stream>>>(m5 + 4 * BTH, g_W, gbuf, BT_, 512, 512, 512, 512, 512, nullptr, nullptr, nullptr);

  rbk_kernel<<<BT_, 256, 0, stream>>>(rbuf, kbuf, bonus, rbk);
  wkv_pass1<<<1024, 128, 0, stream>>>(kbuf, ebuf, vbuf, Sl, Dp);
  wkv_scan<<<1024, 256, 0, stream>>>(Sl, Dp, Ss);
  wkv_pass3<<<1024, 128, 0, stream>>>(rbuf, kbuf, ebuf, vbuf, rbk, Ss, obuf);

  gn_gate_kernel<<<BT_, 256, 0, stream>>>(obuf, gbuf, gnorm_g, gnorm_b);
  mgemm<EPI_RES, 128><<<dim3(64, 4), 256, 0, stream>>>(obuf, o_W, res, BT_, 512, 512, 512, 512, 512, nullptr, x0, nullptr);

  ln1_kernel<<<BT_, 256, 0, stream>>>(res, ffn_g, ffn_b, hf);
  ffnmix_kernel<<<BT_, 256, 0, stream>>>(hf, fk_mu, fr_mu, mfk, mfr);
  mgemm<EPI_RELU2, 128><<<dim3(64, 8), 256, 0, stream>>>(mfk, fk_W, kkb, BT_, 1024, 512, 512, 512, 1024, nullptr, nullptr, nullptr);
  mgemm<EPI_NONE, 128><<<dim3(64, 4), 256, 0, stream>>>(kkb, fv_W, valb, BT_, 512, 1024, 1024, 1024, 512, nullptr, nullptr, nullptr);
  mgemm<EPI_OUT, 128><<<dim3(64, 4), 256, 0, stream>>>(mfr, fr_W, (float*)d_out, BT_, 512, 512, 512, 512, 512, nullptr, res, valb);
}

// Round 5
// 499.230 us; speedup vs baseline: 2.7224x; 1.1873x over previous
//
#include <hip/hip_runtime.h>

// ---------------------------------------------------------------------------
// RWKV6 layer forward, MI355X. Round 4:
//  - GEMM v2: bf16 operand storage everywhere (weights packed once,
//    activations written bf16 by producer epilogues), grouped dispatches
//    (blockIdx.z descriptors) to fix grid starvation, BM/BN templated.
//  - WKV v2: CH=16 (2048 blocks), no vL staging, LDS ~12KB, Sl/Ss bf16.
// ---------------------------------------------------------------------------

#define DEVINL __device__ __forceinline__

constexpr int B_  = 8, T_ = 1024;
constexpr int BT_ = B_ * T_;          // 8192 tokens
constexpr float EPS_ = 1e-5f;
constexpr int CH_ = 16;               // WKV chunk length
constexpr int NC_ = T_ / CH_;         // 64 chunks per sequence

typedef __bf16 bf16x8 __attribute__((ext_vector_type(8)));
typedef float  f32x4  __attribute__((ext_vector_type(4)));

DEVINL unsigned short f2bs(float f) { // fp32 -> bf16 bits, RNE
  union { float f; unsigned int i; } c; c.f = f;
  unsigned int x = c.i;
  return (unsigned short)((x + 0x7fffu + ((x >> 16) & 1u)) >> 16);
}
DEVINL float b2f(unsigned short u) {
  union { unsigned int i; float f; } c; c.i = ((unsigned int)u) << 16; return c.f;
}

DEVINL float block_sum256(float v, float* sb) {
  for (int o = 32; o; o >>= 1) v += __shfl_down(v, o);
  int w = threadIdx.x >> 6;
  __syncthreads();
  if ((threadIdx.x & 63) == 0) sb[w] = v;
  __syncthreads();
  return sb[0] + sb[1] + sb[2] + sb[3];
}

// --------------------------- weight pack ------------------------------------
struct PackSeg { const float* src; int rows, cols, dst_rows; };
struct PackArgs { PackSeg s[12]; int base[13]; };

__global__ __launch_bounds__(256) void pack_kernel(PackArgs pa, unsigned short* dst)
{
  int i = blockIdx.x * 256 + threadIdx.x;
  if (i >= pa.base[12]) return;
  int k = 0;
  while (i >= pa.base[k + 1]) k++;
  int loc = i - pa.base[k];
  PackSeg s = pa.s[k];
  int r = loc / s.cols, c = loc - r * s.cols;
  float v = (r < s.rows) ? s.src[(size_t)r * s.cols + c] : 0.f;
  dst[i] = f2bs(v);
}

// --------------------------- LN kernels ------------------------------------
__global__ __launch_bounds__(256) void ln2_kernel(
    const float* __restrict__ x,
    const float* __restrict__ pg, const float* __restrict__ pb,
    const float* __restrict__ ag, const float* __restrict__ ab,
    float* __restrict__ x0, unsigned short* __restrict__ h)
{
  __shared__ float sb[4];
  size_t base = (size_t)blockIdx.x * 512;
  int tid = threadIdx.x;
  float v0 = x[base + tid], v1 = x[base + 256 + tid];
  float m = block_sum256(v0 + v1, sb) * (1.f / 512.f);
  float d0 = v0 - m, d1 = v1 - m;
  float var = block_sum256(d0 * d0 + d1 * d1, sb) * (1.f / 512.f);
  float rs = rsqrtf(var + EPS_);
  float a0 = d0 * rs * pg[tid]       + pb[tid];
  float a1 = d1 * rs * pg[tid + 256] + pb[tid + 256];
  x0[base + tid] = a0; x0[base + 256 + tid] = a1;
  float m2 = block_sum256(a0 + a1, sb) * (1.f / 512.f);
  float e0 = a0 - m2, e1 = a1 - m2;
  float var2 = block_sum256(e0 * e0 + e1 * e1, sb) * (1.f / 512.f);
  float rs2 = rsqrtf(var2 + EPS_);
  h[base + tid]       = f2bs(e0 * rs2 * ag[tid]       + ab[tid]);
  h[base + 256 + tid] = f2bs(e1 * rs2 * ag[tid + 256] + ab[tid + 256]);
}

__global__ __launch_bounds__(256) void ln1_kernel(
    const float* __restrict__ in,
    const float* __restrict__ g, const float* __restrict__ b,
    float* __restrict__ out)
{
  __shared__ float sb[4];
  size_t base = (size_t)blockIdx.x * 512;
  int tid = threadIdx.x;
  float v0 = in[base + tid], v1 = in[base + 256 + tid];
  float m = block_sum256(v0 + v1, sb) * (1.f / 512.f);
  float d0 = v0 - m, d1 = v1 - m;
  float var = block_sum256(d0 * d0 + d1 * d1, sb) * (1.f / 512.f);
  float rs = rsqrtf(var + EPS_);
  out[base + tid]       = d0 * rs * g[tid]       + b[tid];
  out[base + 256 + tid] = d1 * rs * g[tid + 256] + b[tid + 256];
}

// --------------------------- mix kernels ------------------------------------
__global__ __launch_bounds__(256) void ymix_kernel(
    const unsigned short* __restrict__ h, const float* __restrict__ mu,
    unsigned short* __restrict__ y, unsigned short* __restrict__ dl)
{
  int t = blockIdx.x, tid = threadIdx.x, tt = t & (T_ - 1);
  size_t base = (size_t)t * 512;
  for (int c = tid; c < 512; c += 256) {
    float cur  = b2f(h[base + c]);
    float prev = tt ? b2f(h[base - 512 + c]) : 0.f;
    float d = prev - cur;
    dl[base + c] = f2bs(d);
    y[base + c] = f2bs(cur + d * mu[c]);
  }
}

__global__ __launch_bounds__(256) void ffnmix_kernel(
    const float* __restrict__ hf, const float* __restrict__ fkmu,
    const float* __restrict__ frmu,
    unsigned short* __restrict__ mfk, unsigned short* __restrict__ mfr)
{
  int t = blockIdx.x, tid = threadIdx.x, tt = t & (T_ - 1);
  size_t base = (size_t)t * 512;
  for (int c = tid; c < 512; c += 256) {
    float cur  = hf[base + c];
    float prev = tt ? hf[base - 512 + c] : 0.f;
    float d = prev - cur;
    mfk[base + c] = f2bs(cur + d * fkmu[c]);
    mfr[base + c] = f2bs(cur + d * frmu[c]);
  }
}

// --------------------------- MFMA GEMM v2 -----------------------------------
// C[M=8192,N] = epi(A[M,K] @ W[N,K]^T), A/W bf16 rowmajor. BK=32.
// 256 thr = 4 waves (2x2). Grouped via blockIdx.z descriptor.
enum { EP_NONE_F32 = 0, EP_TANH_BF16 = 1, EP_EXPEXP_F32 = 2, EP_RES_F32 = 3,
       EP_RELU2_BF16 = 4, EP_XMIX_BF16 = 5, EP_OUT2_F32 = 6 };

struct GemmDesc {
  const unsigned short* A; const unsigned short* W; void* C;
  const void* bias; const void* aux1; const void* aux2;
  int N, K, lda, ldw, ldc, epi;
};
template <int NG> struct GD { GemmDesc d[NG]; };

template <int BM, int BN, int NG>
__global__ __launch_bounds__(256) void mgemm(GD<NG> p)
{
  GemmDesc dd = p.d[blockIdx.z];
  int n0 = blockIdx.y * BN;
  if (n0 >= dd.N) return;
  int m0 = blockIdx.x * BM;
  constexpr int MFR = BM / 32, NFR = BN / 32;
  __shared__ short As[BM * 32];            // (BM*4 units) * 8 shorts
  __shared__ short Ws[BN * 32];
  int tid = threadIdx.x, lane = tid & 63, wid = tid >> 6;
  int wm = wid >> 1, wn = wid & 1, lrow = lane & 15, lkg = lane >> 4;

  int arow, akg, wrow, wkg;
  if constexpr (BM == 128) { arow = tid >> 1; akg = (tid & 1) * 2; }
  else                     { arow = tid >> 2; akg = tid & 3; }
  if constexpr (BN == 128) { wrow = tid >> 1; wkg = (tid & 1) * 2; }
  else                     { wrow = tid >> 2; wkg = tid & 3; }
  int uA0 = (akg * (BM / 16) + (arow >> 4)) * 16 + (arow & 15);
  int uA1 = ((akg + 1) * (BM / 16) + (arow >> 4)) * 16 + (arow & 15);
  int uW0 = (wkg * (BN / 16) + (wrow >> 4)) * 16 + (wrow & 15);
  int uW1 = ((wkg + 1) * (BN / 16) + (wrow >> 4)) * 16 + (wrow & 15);

  f32x4 acc[MFR][NFR];
#pragma unroll
  for (int mf = 0; mf < MFR; mf++)
#pragma unroll
    for (int nf = 0; nf < NFR; nf++) acc[mf][nf] = (f32x4){0.f, 0.f, 0.f, 0.f};

  for (int kb = 0; kb < dd.K; kb += 32) {
    const int4* ap = (const int4*)(dd.A + (size_t)(m0 + arow) * dd.lda + kb + akg * 8);
    const int4* wp = (const int4*)(dd.W + (size_t)(n0 + wrow) * dd.ldw + kb + wkg * 8);
    int4 a0 = ap[0], w0 = wp[0], a1, w1;
    if constexpr (BM == 128) a1 = ap[1];
    if constexpr (BN == 128) w1 = wp[1];
    __syncthreads();
    *(int4*)&As[uA0 * 8] = a0;
    if constexpr (BM == 128) *(int4*)&As[uA1 * 8] = a1;
    *(int4*)&Ws[uW0 * 8] = w0;
    if constexpr (BN == 128) *(int4*)&Ws[uW1 * 8] = w1;
    __syncthreads();

    bf16x8 bfrag[NFR];
#pragma unroll
    for (int nf = 0; nf < NFR; nf++)
      bfrag[nf] = *(const bf16x8*)&Ws[((lkg * (BN / 16) + wn * NFR + nf) * 16 + lrow) * 8];
#pragma unroll
    for (int mf = 0; mf < MFR; mf++) {
      bf16x8 afrag = *(const bf16x8*)&As[((lkg * (BM / 16) + wm * MFR + mf) * 16 + lrow) * 8];
#pragma unroll
      for (int nf = 0; nf < NFR; nf++)
        acc[mf][nf] = __builtin_amdgcn_mfma_f32_16x16x32_bf16(
            afrag, bfrag[nf], acc[mf][nf], 0, 0, 0);
    }
  }

#pragma unroll
  for (int mf = 0; mf < MFR; mf++) {
#pragma unroll
    for (int nf = 0; nf < NFR; nf++) {
#pragma unroll
      for (int r = 0; r < 4; r++) {
        int m = m0 + wm * (MFR * 16) + mf * 16 + (lane >> 4) * 4 + r;
        int n = n0 + wn * (NFR * 16) + nf * 16 + lrow;
        size_t off = (size_t)m * dd.ldc + n;
        float c = acc[mf][nf][r];
        switch (dd.epi) {
          case EP_NONE_F32:
            ((float*)dd.C)[off] = c; break;
          case EP_TANH_BF16:
            ((unsigned short*)dd.C)[off] = f2bs(tanhf(c)); break;
          case EP_EXPEXP_F32:
            ((float*)dd.C)[off] = expf(-expf(c + ((const float*)dd.bias)[n])); break;
          case EP_RES_F32:
            ((float*)dd.C)[off] = c + ((const float*)dd.aux1)[off]; break;
          case EP_RELU2_BF16: {
            c = fmaxf(c, 0.f);
            ((unsigned short*)dd.C)[off] = f2bs(c * c); break;
          }
          case EP_XMIX_BF16: {
            float hv = b2f(((const unsigned short*)dd.aux1)[off]);
            float dv = b2f(((const unsigned short*)dd.aux2)[off]);
            ((unsigned short*)dd.C)[off] =
                f2bs(hv + dv * (c + ((const float*)dd.bias)[n])); break;
          }
          case EP_OUT2_F32: {
            float fr = ((const float*)dd.aux2)[off];
            ((float*)dd.C)[off] = ((const float*)dd.aux1)[off]
                                  + (1.f / (1.f + expf(-fr))) * c; break;
          }
        }
      }
    }
  }
}

// --------------------------- bonus scalar ----------------------------------
__global__ __launch_bounds__(256) void rbk_kernel(
    const float* __restrict__ r, const float* __restrict__ k,
    const float* __restrict__ bonus, float* __restrict__ rbk)
{
  int t = blockIdx.x, tid = threadIdx.x;
  int hh = tid >> 6, j = tid & 63;
  size_t g = (size_t)t * 256 + hh * 64 + j;
  float p = r[g] * k[g] * bonus[hh * 64 + j];
  for (int o = 32; o; o >>= 1) p += __shfl_down(p, o);
  if (j == 0) rbk[(size_t)t * 4 + hh] = p;
}

// --------------------------- WKV 3-pass chunked scan (CH=16) ----------------
__global__ __launch_bounds__(128) void wkv_pass1(
    const float* __restrict__ k, const float* __restrict__ ew,
    const float* __restrict__ v, unsigned short* __restrict__ Sl,
    float* __restrict__ Dp)
{
  __shared__ float kL[CH_][64], eL[CH_][64];
  int blk = blockIdx.x;
  int c = blk & (NC_ - 1), bh = blk >> 6;
  int b = bh >> 2, hh = bh & 3;
  int tid = threadIdx.x;
  size_t tbase = (size_t)b * T_ + (size_t)c * CH_;
  for (int idx = tid; idx < CH_ * 64; idx += 128) {
    int s = idx >> 6, j = idx & 63;
    size_t g = (tbase + s) * 256 + hh * 64 + j;
    kL[s][j] = k[g]; eL[s][j] = ew[g];
  }
  __syncthreads();
  float S[64];
#pragma unroll
  for (int j = 0; j < 64; j++) S[j] = 0.f;
  for (int s = 0; s < CH_; s++) {
    float vv = v[(tbase + s) * 512 + hh * 128 + tid];
    const float4* e4p = (const float4*)&eL[s][0];
    const float4* k4p = (const float4*)&kL[s][0];
#pragma unroll
    for (int q = 0; q < 16; q++) {
      float4 e4 = e4p[q], k4 = k4p[q];
      S[4 * q + 0] = e4.x * S[4 * q + 0] + k4.x * vv;
      S[4 * q + 1] = e4.y * S[4 * q + 1] + k4.y * vv;
      S[4 * q + 2] = e4.z * S[4 * q + 2] + k4.z * vv;
      S[4 * q + 3] = e4.w * S[4 * q + 3] + k4.w * vv;
    }
  }
  size_t sbase = (size_t)blk * 8192;
#pragma unroll
  for (int j = 0; j < 64; j++) Sl[sbase + j * 128 + tid] = f2bs(S[j]);
  if (tid < 64) {
    float d = 1.f;
    for (int s = 0; s < CH_; s++) d *= eL[s][tid];
    Dp[(size_t)blk * 64 + tid] = d;
  }
}

__global__ __launch_bounds__(256) void wkv_scan(
    const unsigned short* __restrict__ Sl, const float* __restrict__ Dp,
    unsigned short* __restrict__ Ss)
{
  int e = blockIdx.x * 256 + threadIdx.x;   // < 32*8192
  int bh = e >> 13; int kv = e & 8191; int j = kv >> 7;
  float run = 0.f;
  for (int c = 0; c < NC_; c++) {
    size_t base = (size_t)bh * NC_ + c;
    Ss[base * 8192 + kv] = f2bs(run);
    run = Dp[base * 64 + j] * run + b2f(Sl[base * 8192 + kv]);
  }
}

__global__ __launch_bounds__(128) void wkv_pass3(
    const float* __restrict__ r, const float* __restrict__ k,
    const float* __restrict__ ew, const float* __restrict__ v,
    const float* __restrict__ rbk, const unsigned short* __restrict__ Ss,
    float* __restrict__ o)
{
  __shared__ float rL[CH_][64], kL[CH_][64], eL[CH_][64], rbL[CH_];
  int blk = blockIdx.x;
  int c = blk & (NC_ - 1), bh = blk >> 6;
  int b = bh >> 2, hh = bh & 3;
  int tid = threadIdx.x;
  size_t tbase = (size_t)b * T_ + (size_t)c * CH_;
  for (int idx = tid; idx < CH_ * 64; idx += 128) {
    int s = idx >> 6, j = idx & 63;
    size_t g = (tbase + s) * 256 + hh * 64 + j;
    rL[s][j] = r[g]; kL[s][j] = k[g]; eL[s][j] = ew[g];
  }
  if (tid < CH_) rbL[tid] = rbk[(tbase + tid) * 4 + hh];
  __syncthreads();
  float S[64];
  size_t sbase = (size_t)blk * 8192;
#pragma unroll
  for (int j = 0; j < 64; j++) S[j] = b2f(Ss[sbase + j * 128 + tid]);
  for (int s = 0; s < CH_; s++) {
    float vv = v[(tbase + s) * 512 + hh * 128 + tid];
    float oa = rbL[s] * vv;
    const float4* r4p = (const float4*)&rL[s][0];
    const float4* e4p = (const float4*)&eL[s][0];
    const float4* k4p = (const float4*)&kL[s][0];
#pragma unroll
    for (int q = 0; q < 16; q++) {
      float4 r4 = r4p[q], e4 = e4p[q], k4 = k4p[q];
      oa += r4.x * S[4 * q + 0] + r4.y * S[4 * q + 1]
          + r4.z * S[4 * q + 2] + r4.w * S[4 * q + 3];
      S[4 * q + 0] = e4.x * S[4 * q + 0] + k4.x * vv;
      S[4 * q + 1] = e4.y * S[4 * q + 1] + k4.y * vv;
      S[4 * q + 2] = e4.z * S[4 * q + 2] + k4.z * vv;
      S[4 * q + 3] = e4.w * S[4 * q + 3] + k4.w * vv;
    }
    o[(tbase + s) * 512 + hh * 128 + tid] = oa;
  }
}

// --------------------------- groupnorm + swish gate -------------------------
__global__ __launch_bounds__(256) void gn_gate_kernel(
    const float* __restrict__ o, const float* __restrict__ g,
    const float* __restrict__ gg, const float* __restrict__ gb,
    unsigned short* __restrict__ obf)
{
  __shared__ float ov[512], ps[64], qs[64], mh[4], vh[4];
  int t = blockIdx.x, tid = threadIdx.x;
  size_t base = (size_t)t * 512;
  ov[tid] = o[base + tid]; ov[tid + 256] = o[base + 256 + tid];
  __syncthreads();
  if (tid < 64) {
    int hh = tid >> 4, sg = tid & 15;
    const float* p = &ov[hh * 128 + sg * 8];
    float s = 0.f, q = 0.f;
    for (int i = 0; i < 8; i++) { s += p[i]; q += p[i] * p[i]; }
    ps[tid] = s; qs[tid] = q;
  }
  __syncthreads();
  if (tid < 4) {
    float s = 0.f, q = 0.f;
    for (int i = 0; i < 16; i++) { s += ps[tid * 16 + i]; q += qs[tid * 16 + i]; }
    float m = s * (1.f / 128.f);
    mh[tid] = m; vh[tid] = q * (1.f / 128.f) - m * m;
  }
  __syncthreads();
  for (int c = tid; c < 512; c += 256) {
    int hh = c >> 7;
    float nrm = (ov[c] - mh[hh]) * rsqrtf(vh[hh] + EPS_);
    float gv = g[base + c];
    float sw = gv * (1.f / (1.f + expf(-gv)));
    obf[base + c] = f2bs((nrm * gg[c] + gb[c]) * sw);
  }
}

// ---------------------------------------------------------------------------
extern "C" void kernel_launch(void* const* d_in, const int* in_sizes, int n_in,
                              void* d_out, int out_size, void* d_ws, size_t ws_size,
                              hipStream_t stream) {
  (void)in_sizes; (void)n_in; (void)out_size; (void)ws_size;
  const float* x        = (const float*)d_in[0];
  const float* pre_g    = (const float*)d_in[1];
  const float* pre_b    = (const float*)d_in[2];
  const float* attn_g   = (const float*)d_in[3];
  const float* attn_b   = (const float*)d_in[4];
  const float* ffn_g    = (const float*)d_in[5];
  const float* ffn_b    = (const float*)d_in[6];
  const float* xproj_mu = (const float*)d_in[7];
  const float* xproj_w1 = (const float*)d_in[8];
  const float* xproj_w2 = (const float*)d_in[9];
  const float* x_bias   = (const float*)d_in[10];
  const float* r_W      = (const float*)d_in[11];
  const float* w_W1     = (const float*)d_in[12];
  const float* w_W2     = (const float*)d_in[13];
  const float* w_b      = (const float*)d_in[14];
  const float* k_W      = (const float*)d_in[15];
  const float* v_W      = (const float*)d_in[16];
  const float* g_W      = (const float*)d_in[17];
  const float* bonus    = (const float*)d_in[18];
  const float* gnorm_g  = (const float*)d_in[19];
  const float* gnorm_b  = (const float*)d_in[20];
  const float* o_W      = (const float*)d_in[21];
  const float* fk_mu    = (const float*)d_in[22];
  const float* fk_W     = (const float*)d_in[23];
  const float* fv_W     = (const float*)d_in[24];
  const float* fr_mu    = (const float*)d_in[25];
  const float* fr_W     = (const float*)d_in[26];

  const size_t BTH = (size_t)BT_ * 512;  // 4,194,304
  size_t cur = 0;
  auto alloc = [&](size_t bytes) { void* p = (char*)d_ws + cur; cur += (bytes + 255) & ~(size_t)255; return p; };
  float*          x0    = (float*)alloc(BTH * 4);
  unsigned short* hbufb = (unsigned short*)alloc(BTH * 2);
  unsigned short* m5b   = (unsigned short*)alloc(5 * BTH * 2);   // 40MB
  float*          rbuf  = (float*)alloc((size_t)BT_ * 256 * 4);  // 8MB
  float*          kbuf  = (float*)alloc((size_t)BT_ * 256 * 4);  // 8MB
  float*          ebuf  = (float*)alloc((size_t)BT_ * 256 * 4);  // 8MB
  float*          vbuf  = (float*)alloc(BTH * 4);                // 16MB
  float*          gbuf  = (float*)alloc(BTH * 4);                // 16MB
  unsigned short* wtmpb = (unsigned short*)alloc((size_t)BT_ * 128 * 2); // 2MB
  float*          rbk   = (float*)alloc((size_t)BT_ * 4 * 4);
  unsigned short* Sl    = (unsigned short*)alloc((size_t)2048 * 8192 * 2); // 32MB
  unsigned short* Ss    = (unsigned short*)alloc((size_t)2048 * 8192 * 2); // 32MB
  float*          Dp    = (float*)alloc((size_t)2048 * 64 * 4);  // 512KB
  float*          res   = (float*)alloc(BTH * 4);                // 16MB
  unsigned short* wpack = (unsigned short*)alloc((size_t)2621440 * 2);
  // aliases (occupant dead before writer runs):
  unsigned short* ybufb = (unsigned short*)rbuf;   // 8MB, dead before r-GEMM
  unsigned short* dlb   = (unsigned short*)vbuf;   // 8MB, dead before v-GEMM
  unsigned short* z5b   = (unsigned short*)gbuf;   // 3MB, dead before g-GEMM
  float*          obuf  = (float*)m5b;             // 16MB, m5 dead after setA
  unsigned short* obf16 = (unsigned short*)ebuf;   // 8MB, ebuf dead after pass3
  float*          hf    = x0;                      // x0 dead after oW-RES
  unsigned short* mfk   = (unsigned short*)rbuf;   // dead after pass3
  unsigned short* mfr   = (unsigned short*)kbuf;   // dead after pass3
  unsigned short* kkb   = Sl;                      // Sl dead after scan
  float*          frtmp = vbuf;                    // vbuf dead after pass3

  // packed weight offsets (elements)
  PackArgs pa;
  int off = 0, seg = 0;
  auto addseg = [&](const float* src, int rows, int cols, int dst_rows) {
    pa.s[seg] = {src, rows, cols, dst_rows};
    pa.base[seg] = off; off += dst_rows * cols; seg++;
  };
  addseg(xproj_w1, 160, 512, 192);   int o_w1p = pa.base[0];
  addseg(w_W1,      64, 512, 128);   int o_wW1 = pa.base[1];
  addseg(r_W,      256, 512, 256);   int o_rW  = pa.base[2];
  addseg(k_W,      256, 512, 256);   int o_kW  = pa.base[3];
  addseg(v_W,      512, 512, 512);   int o_vW  = pa.base[4];
  addseg(g_W,      512, 512, 512);   int o_gW  = pa.base[5];
  addseg(o_W,      512, 512, 512);   int o_oW  = pa.base[6];
  addseg(fk_W,    1024, 512, 1024);  int o_fkW = pa.base[7];
  addseg(fv_W,     512, 1024, 512);  int o_fvW = pa.base[8];
  addseg(fr_W,     512, 512, 512);   int o_frW = pa.base[9];
  addseg(w_W2,     256, 64, 256);    int o_wW2 = pa.base[10];
  addseg(xproj_w2, 512, 160, 512);   int o_xw2 = pa.base[11];
  pa.base[12] = off;

  pack_kernel<<<(off + 255) / 256, 256, 0, stream>>>(pa, wpack);
  ln2_kernel<<<BT_, 256, 0, stream>>>(x, pre_g, pre_b, attn_g, attn_b, x0, hbufb);
  ymix_kernel<<<BT_, 256, 0, stream>>>(hbufb, xproj_mu, ybufb, dlb);

  auto solo = [&](const unsigned short* A, const unsigned short* W, void* C,
                  const void* bias, const void* a1, const void* a2,
                  int N, int K, int lda, int ldw, int ldc, int epi) {
    GD<1> g; g.d[0] = {A, W, C, bias, a1, a2, N, K, lda, ldw, ldc, epi};
    mgemm<64, 64, 1><<<dim3(128, (N + 63) / 64, 1), 256, 0, stream>>>(g);
  };

  // z5 = tanh(Y @ W1p^T), N=192
  solo(ybufb, wpack + o_w1p, z5b, nullptr, nullptr, nullptr,
       192, 512, 512, 512, 192, EP_TANH_BF16);

  // set B: 5 xmix GEMMs (K=32) -> m5 slots (bf16)
  {
    GD<5> g;
    for (int n = 0; n < 5; n++)
      g.d[n] = {z5b + n * 32, wpack + o_xw2 + n * 32, m5b + (size_t)n * BTH,
                x_bias + n * 512, hbufb, dlb, 512, 32, 192, 160, 512, EP_XMIX_BF16};
    mgemm<128, 128, 5><<<dim3(64, 4, 5), 256, 0, stream>>>(g);
  }

  // set A: r, w1, k, v, g projections (K=512)
  {
    GD<5> g;
    g.d[0] = {m5b + 0 * BTH, wpack + o_rW, rbuf, nullptr, nullptr, nullptr, 256, 512, 512, 512, 256, EP_NONE_F32};
    g.d[1] = {m5b + 1 * BTH, wpack + o_wW1, wtmpb, nullptr, nullptr, nullptr, 128, 512, 512, 512, 128, EP_TANH_BF16};
    g.d[2] = {m5b + 2 * BTH, wpack + o_kW, kbuf, nullptr, nullptr, nullptr, 256, 512, 512, 512, 256, EP_NONE_F32};
    g.d[3] = {m5b + 3 * BTH, wpack + o_vW, vbuf, nullptr, nullptr, nullptr, 512, 512, 512, 512, 512, EP_NONE_F32};
    g.d[4] = {m5b + 4 * BTH, wpack + o_gW, gbuf, nullptr, nullptr, nullptr, 512, 512, 512, 512, 512, EP_NONE_F32};
    mgemm<128, 128, 5><<<dim3(64, 4, 5), 256, 0, stream>>>(g);
  }

  // decay: ebuf = exp(-exp(wtmp @ w_W2^T + w_b)), K=64
  solo(wtmpb, wpack + o_wW2, ebuf, w_b, nullptr, nullptr,
       256, 64, 128, 64, 256, EP_EXPEXP_F32);

  rbk_kernel<<<BT_, 256, 0, stream>>>(rbuf, kbuf, bonus, rbk);
  wkv_pass1<<<2048, 128, 0, stream>>>(kbuf, ebuf, vbuf, Sl, Dp);
  wkv_scan<<<1024, 256, 0, stream>>>(Sl, Dp, Ss);
  wkv_pass3<<<2048, 128, 0, stream>>>(rbuf, kbuf, ebuf, vbuf, rbk, Ss, obuf);

  gn_gate_kernel<<<BT_, 256, 0, stream>>>(obuf, gbuf, gnorm_g, gnorm_b, obf16);

  // res = o @ o_W^T + x0
  solo(obf16, wpack + o_oW, res, nullptr, x0, nullptr,
       512, 512, 512, 512, 512, EP_RES_F32);

  ln1_kernel<<<BT_, 256, 0, stream>>>(res, ffn_g, ffn_b, hf);
  ffnmix_kernel<<<BT_, 256, 0, stream>>>(hf, fk_mu, fr_mu, mfk, mfr);

  // set C: fk (relu^2 -> kkb) and fr (-> frtmp), both K=512
  {
    GD<2> g;
    g.d[0] = {mfk, wpack + o_fkW, kkb, nullptr, nullptr, nullptr, 1024, 512, 512, 512, 1024, EP_RELU2_BF16};
    g.d[1] = {mfr, wpack + o_frW, frtmp, nullptr, nullptr, nullptr, 512, 512, 512, 512, 512, EP_NONE_F32};
    mgemm<128, 128, 2><<<dim3(64, 8, 2), 256, 0, stream>>>(g);
  }

  // out = res + sigmoid(frtmp) * (kk @ fv_W^T), K=1024
  solo(kkb, wpack + o_fvW, (float*)d_out, nullptr, res, frtmp,
       512, 1024, 1024, 1024, 512, EP_OUT2_F32);
}

// Round 6
// 361.691 us; speedup vs baseline: 3.7576x; 1.3803x over previous
//
#include <hip/hip_runtime.h>

// ---------------------------------------------------------------------------
// RWKV6 layer forward, MI355X. Round 5:
//  - mgemm: transposed MFMA (mfma(W,A)) -> lane holds 4 consecutive n ->
//    vectorized stores (float4 / packed uint2). No more write amplification.
//  - xmix: dedicated fused kernel (was a K=32 GEMM group at 115us).
//  - r/k/v stored bf16 (set A writes halved; wkv reads bf16).
// ---------------------------------------------------------------------------

#define DEVINL __device__ __forceinline__

constexpr int B_  = 8, T_ = 1024;
constexpr int BT_ = B_ * T_;          // 8192 tokens
constexpr float EPS_ = 1e-5f;
constexpr int CH_ = 16;               // WKV chunk length
constexpr int NC_ = T_ / CH_;         // 64 chunks per sequence

typedef __bf16 bf16x8 __attribute__((ext_vector_type(8)));
typedef float  f32x4  __attribute__((ext_vector_type(4)));

DEVINL unsigned short f2bs(float f) { // fp32 -> bf16 bits, RNE
  union { float f; unsigned int i; } c; c.f = f;
  unsigned int x = c.i;
  return (unsigned short)((x + 0x7fffu + ((x >> 16) & 1u)) >> 16);
}
DEVINL float b2f(unsigned short u) {
  union { unsigned int i; float f; } c; c.i = ((unsigned int)u) << 16; return c.f;
}

DEVINL float block_sum256(float v, float* sb) {
  for (int o = 32; o; o >>= 1) v += __shfl_down(v, o);
  int w = threadIdx.x >> 6;
  __syncthreads();
  if ((threadIdx.x & 63) == 0) sb[w] = v;
  __syncthreads();
  return sb[0] + sb[1] + sb[2] + sb[3];
}

// --------------------------- weight pack ------------------------------------
struct PackSeg { const float* src; int rows, cols, dst_rows; };
struct PackArgs { PackSeg s[12]; int base[13]; };

__global__ __launch_bounds__(256) void pack_kernel(PackArgs pa, unsigned short* dst)
{
  int i = blockIdx.x * 256 + threadIdx.x;
  if (i >= pa.base[12]) return;
  int k = 0;
  while (i >= pa.base[k + 1]) k++;
  int loc = i - pa.base[k];
  PackSeg s = pa.s[k];
  int r = loc / s.cols, c = loc - r * s.cols;
  float v = (r < s.rows) ? s.src[(size_t)r * s.cols + c] : 0.f;
  dst[i] = f2bs(v);
}

// --------------------------- LN kernels ------------------------------------
__global__ __launch_bounds__(256) void ln2_kernel(
    const float* __restrict__ x,
    const float* __restrict__ pg, const float* __restrict__ pb,
    const float* __restrict__ ag, const float* __restrict__ ab,
    float* __restrict__ x0, unsigned short* __restrict__ h)
{
  __shared__ float sb[4];
  size_t base = (size_t)blockIdx.x * 512;
  int tid = threadIdx.x;
  float v0 = x[base + tid], v1 = x[base + 256 + tid];
  float m = block_sum256(v0 + v1, sb) * (1.f / 512.f);
  float d0 = v0 - m, d1 = v1 - m;
  float var = block_sum256(d0 * d0 + d1 * d1, sb) * (1.f / 512.f);
  float rs = rsqrtf(var + EPS_);
  float a0 = d0 * rs * pg[tid]       + pb[tid];
  float a1 = d1 * rs * pg[tid + 256] + pb[tid + 256];
  x0[base + tid] = a0; x0[base + 256 + tid] = a1;
  float m2 = block_sum256(a0 + a1, sb) * (1.f / 512.f);
  float e0 = a0 - m2, e1 = a1 - m2;
  float var2 = block_sum256(e0 * e0 + e1 * e1, sb) * (1.f / 512.f);
  float rs2 = rsqrtf(var2 + EPS_);
  h[base + tid]       = f2bs(e0 * rs2 * ag[tid]       + ab[tid]);
  h[base + 256 + tid] = f2bs(e1 * rs2 * ag[tid + 256] + ab[tid + 256]);
}

__global__ __launch_bounds__(256) void ln1_kernel(
    const float* __restrict__ in,
    const float* __restrict__ g, const float* __restrict__ b,
    float* __restrict__ out)
{
  __shared__ float sb[4];
  size_t base = (size_t)blockIdx.x * 512;
  int tid = threadIdx.x;
  float v0 = in[base + tid], v1 = in[base + 256 + tid];
  float m = block_sum256(v0 + v1, sb) * (1.f / 512.f);
  float d0 = v0 - m, d1 = v1 - m;
  float var = block_sum256(d0 * d0 + d1 * d1, sb) * (1.f / 512.f);
  float rs = rsqrtf(var + EPS_);
  out[base + tid]       = d0 * rs * g[tid]       + b[tid];
  out[base + 256 + tid] = d1 * rs * g[tid + 256] + b[tid + 256];
}

// --------------------------- mix kernels ------------------------------------
__global__ __launch_bounds__(256) void ymix_kernel(
    const unsigned short* __restrict__ h, const float* __restrict__ mu,
    unsigned short* __restrict__ y, unsigned short* __restrict__ dl)
{
  int t = blockIdx.x, tid = threadIdx.x, tt = t & (T_ - 1);
  size_t base = (size_t)t * 512;
  for (int c = tid; c < 512; c += 256) {
    float cur  = b2f(h[base + c]);
    float prev = tt ? b2f(h[base - 512 + c]) : 0.f;
    float d = prev - cur;
    dl[base + c] = f2bs(d);
    y[base + c] = f2bs(cur + d * mu[c]);
  }
}

__global__ __launch_bounds__(256) void ffnmix_kernel(
    const float* __restrict__ hf, const float* __restrict__ fkmu,
    const float* __restrict__ frmu,
    unsigned short* __restrict__ mfk, unsigned short* __restrict__ mfr)
{
  int t = blockIdx.x, tid = threadIdx.x, tt = t & (T_ - 1);
  size_t base = (size_t)t * 512;
  for (int c = tid; c < 512; c += 256) {
    float cur  = hf[base + c];
    float prev = tt ? hf[base - 512 + c] : 0.f;
    float d = prev - cur;
    mfk[base + c] = f2bs(cur + d * fkmu[c]);
    mfr[base + c] = f2bs(cur + d * frmu[c]);
  }
}

// --------------------------- xmix (fused) -----------------------------------
// m5[n][t][c] = h[t][c] + dl[t][c] * (dot32(z5[t][n*32..], W2[c][n*32..]) + xb[n][c])
// 8 tokens per block; W2 row (20 int4) held in regs across the 8 tokens.
constexpr int TPB_ = 8;
__global__ __launch_bounds__(256) void xmix5_kernel(
    const unsigned short* __restrict__ z5,   // [8192][192] bf16 (ld 192)
    const unsigned short* __restrict__ w2,   // [512][160] bf16
    const float* __restrict__ xbias,         // [5][512]
    const unsigned short* __restrict__ h, const unsigned short* __restrict__ dl,
    unsigned short* __restrict__ m5)
{
  __shared__ float zL[TPB_][160];
  int t0 = blockIdx.x * TPB_;
  int tid = threadIdx.x;
  for (int i = tid; i < TPB_ * 160; i += 256) {
    int tt = i / 160, kk = i - tt * 160;
    zL[tt][kk] = b2f(z5[(size_t)(t0 + tt) * 192 + kk]);
  }
  __syncthreads();
  for (int half = 0; half < 2; half++) {
    int c = tid + half * 256;
    const int4* wp = (const int4*)(w2 + (size_t)c * 160);
    int4 wv[20];
#pragma unroll
    for (int q = 0; q < 20; q++) wv[q] = wp[q];
    float bia[5];
#pragma unroll
    for (int n = 0; n < 5; n++) bia[n] = xbias[n * 512 + c];
    for (int tt = 0; tt < TPB_; tt++) {
      size_t base = (size_t)(t0 + tt) * 512 + c;
      float hv = b2f(h[base]), dv = b2f(dl[base]);
#pragma unroll
      for (int n = 0; n < 5; n++) {
        float a = 0.f;
#pragma unroll
        for (int q = 0; q < 4; q++) {
          const unsigned short* u = (const unsigned short*)&wv[n * 4 + q];
          const float* z = &zL[tt][n * 32 + q * 8];
#pragma unroll
          for (int j = 0; j < 8; j++) a += b2f(u[j]) * z[j];
        }
        m5[(size_t)n * ((size_t)BT_ * 512) + base] = f2bs(hv + dv * (a + bia[n]));
      }
    }
  }
}

// --------------------------- MFMA GEMM v3 -----------------------------------
// C[M,N] = epi(A[M,K] @ W[N,K]^T). Transposed fragments: mfma(W,A) so each
// lane holds 4 consecutive n -> vectorized stores.
enum { EP_NONE_F32 = 0, EP_NONE_BF16 = 1, EP_TANH_BF16 = 2, EP_EXPEXP_F32 = 3,
       EP_RES_F32 = 4, EP_RELU2_BF16 = 5, EP_OUT2_F32 = 6 };

struct GemmDesc {
  const unsigned short* A; const unsigned short* W; void* C;
  const void* bias; const void* aux1; const void* aux2;
  int N, K, lda, ldw, ldc, epi;
};
template <int NG> struct GD { GemmDesc d[NG]; };

template <int BM, int BN, int NG>
__global__ __launch_bounds__(256) void mgemm(GD<NG> p)
{
  GemmDesc dd = p.d[blockIdx.z];
  int n0 = blockIdx.y * BN;
  if (n0 >= dd.N) return;
  int m0 = blockIdx.x * BM;
  constexpr int MFR = BM / 32, NFR = BN / 32;
  __shared__ short As[BM * 32];
  __shared__ short Ws[BN * 32];
  int tid = threadIdx.x, lane = tid & 63, wid = tid >> 6;
  int wm = wid >> 1, wn = wid & 1, lrow = lane & 15, lkg = lane >> 4;

  int arow, akg, wrow, wkg;
  if constexpr (BM == 128) { arow = tid >> 1; akg = (tid & 1) * 2; }
  else                     { arow = tid >> 2; akg = tid & 3; }
  if constexpr (BN == 128) { wrow = tid >> 1; wkg = (tid & 1) * 2; }
  else                     { wrow = tid >> 2; wkg = tid & 3; }
  int uA0 = (akg * (BM / 16) + (arow >> 4)) * 16 + (arow & 15);
  int uA1 = ((akg + 1) * (BM / 16) + (arow >> 4)) * 16 + (arow & 15);
  int uW0 = (wkg * (BN / 16) + (wrow >> 4)) * 16 + (wrow & 15);
  int uW1 = ((wkg + 1) * (BN / 16) + (wrow >> 4)) * 16 + (wrow & 15);

  f32x4 acc[MFR][NFR];
#pragma unroll
  for (int mf = 0; mf < MFR; mf++)
#pragma unroll
    for (int nf = 0; nf < NFR; nf++) acc[mf][nf] = (f32x4){0.f, 0.f, 0.f, 0.f};

  for (int kb = 0; kb < dd.K; kb += 32) {
    const int4* ap = (const int4*)(dd.A + (size_t)(m0 + arow) * dd.lda + kb + akg * 8);
    const int4* wp = (const int4*)(dd.W + (size_t)(n0 + wrow) * dd.ldw + kb + wkg * 8);
    int4 a0 = ap[0], w0 = wp[0], a1, w1;
    if constexpr (BM == 128) a1 = ap[1];
    if constexpr (BN == 128) w1 = wp[1];
    __syncthreads();
    *(int4*)&As[uA0 * 8] = a0;
    if constexpr (BM == 128) *(int4*)&As[uA1 * 8] = a1;
    *(int4*)&Ws[uW0 * 8] = w0;
    if constexpr (BN == 128) *(int4*)&Ws[uW1 * 8] = w1;
    __syncthreads();

    bf16x8 bfrag[NFR];
#pragma unroll
    for (int nf = 0; nf < NFR; nf++)
      bfrag[nf] = *(const bf16x8*)&Ws[((lkg * (BN / 16) + wn * NFR + nf) * 16 + lrow) * 8];
#pragma unroll
    for (int mf = 0; mf < MFR; mf++) {
      bf16x8 afrag = *(const bf16x8*)&As[((lkg * (BM / 16) + wm * MFR + mf) * 16 + lrow) * 8];
#pragma unroll
      for (int nf = 0; nf < NFR; nf++)
        acc[mf][nf] = __builtin_amdgcn_mfma_f32_16x16x32_bf16(
            bfrag[nf], afrag, acc[mf][nf], 0, 0, 0);   // D rows = n
    }
  }

#pragma unroll
  for (int mf = 0; mf < MFR; mf++) {
#pragma unroll
    for (int nf = 0; nf < NFR; nf++) {
      int m  = m0 + wm * (MFR * 16) + mf * 16 + lrow;
      int nb = n0 + wn * (NFR * 16) + nf * 16 + lkg * 4;
      size_t off = (size_t)m * dd.ldc + nb;
      float c0 = acc[mf][nf][0], c1 = acc[mf][nf][1];
      float c2 = acc[mf][nf][2], c3 = acc[mf][nf][3];
      switch (dd.epi) {
        case EP_NONE_F32: {
          f32x4 v = {c0, c1, c2, c3};
          *(f32x4*)((float*)dd.C + off) = v; break;
        }
        case EP_NONE_BF16: {
          uint2 u; u.x = f2bs(c0) | ((unsigned)f2bs(c1) << 16);
          u.y = f2bs(c2) | ((unsigned)f2bs(c3) << 16);
          *(uint2*)((unsigned short*)dd.C + off) = u; break;
        }
        case EP_TANH_BF16: {
          uint2 u; u.x = f2bs(tanhf(c0)) | ((unsigned)f2bs(tanhf(c1)) << 16);
          u.y = f2bs(tanhf(c2)) | ((unsigned)f2bs(tanhf(c3)) << 16);
          *(uint2*)((unsigned short*)dd.C + off) = u; break;
        }
        case EP_EXPEXP_F32: {
          const float* bi = (const float*)dd.bias;
          f32x4 v = {expf(-expf(c0 + bi[nb + 0])), expf(-expf(c1 + bi[nb + 1])),
                     expf(-expf(c2 + bi[nb + 2])), expf(-expf(c3 + bi[nb + 3]))};
          *(f32x4*)((float*)dd.C + off) = v; break;
        }
        case EP_RES_F32: {
          f32x4 a = *(const f32x4*)((const float*)dd.aux1 + off);
          f32x4 v = {c0 + a[0], c1 + a[1], c2 + a[2], c3 + a[3]};
          *(f32x4*)((float*)dd.C + off) = v; break;
        }
        case EP_RELU2_BF16: {
          c0 = fmaxf(c0, 0.f); c1 = fmaxf(c1, 0.f);
          c2 = fmaxf(c2, 0.f); c3 = fmaxf(c3, 0.f);
          uint2 u; u.x = f2bs(c0 * c0) | ((unsigned)f2bs(c1 * c1) << 16);
          u.y = f2bs(c2 * c2) | ((unsigned)f2bs(c3 * c3) << 16);
          *(uint2*)((unsigned short*)dd.C + off) = u; break;
        }
        case EP_OUT2_F32: {
          f32x4 rs = *(const f32x4*)((const float*)dd.aux1 + off);
          f32x4 fr = *(const f32x4*)((const float*)dd.aux2 + off);
          f32x4 v = {rs[0] + (1.f / (1.f + expf(-fr[0]))) * c0,
                     rs[1] + (1.f / (1.f + expf(-fr[1]))) * c1,
                     rs[2] + (1.f / (1.f + expf(-fr[2]))) * c2,
                     rs[3] + (1.f / (1.f + expf(-fr[3]))) * c3};
          *(f32x4*)((float*)dd.C + off) = v; break;
        }
      }
    }
  }
}

// --------------------------- bonus scalar ----------------------------------
__global__ __launch_bounds__(256) void rbk_kernel(
    const unsigned short* __restrict__ r, const unsigned short* __restrict__ k,
    const float* __restrict__ bonus, float* __restrict__ rbk)
{
  int t = blockIdx.x, tid = threadIdx.x;
  int hh = tid >> 6, j = tid & 63;
  size_t g = (size_t)t * 256 + hh * 64 + j;
  float p = b2f(r[g]) * b2f(k[g]) * bonus[hh * 64 + j];
  for (int o = 32; o; o >>= 1) p += __shfl_down(p, o);
  if (j == 0) rbk[(size_t)t * 4 + hh] = p;
}

// --------------------------- WKV 3-pass chunked scan (CH=16) ----------------
__global__ __launch_bounds__(128) void wkv_pass1(
    const unsigned short* __restrict__ k, const float* __restrict__ ew,
    const unsigned short* __restrict__ v, unsigned short* __restrict__ Sl,
    float* __restrict__ Dp)
{
  __shared__ float kL[CH_][64], eL[CH_][64];
  int blk = blockIdx.x;
  int c = blk & (NC_ - 1), bh = blk >> 6;
  int b = bh >> 2, hh = bh & 3;
  int tid = threadIdx.x;
  size_t tbase = (size_t)b * T_ + (size_t)c * CH_;
  for (int idx = tid; idx < CH_ * 64; idx += 128) {
    int s = idx >> 6, j = idx & 63;
    size_t g = (tbase + s) * 256 + hh * 64 + j;
    kL[s][j] = b2f(k[g]); eL[s][j] = ew[g];
  }
  __syncthreads();
  float S[64];
#pragma unroll
  for (int j = 0; j < 64; j++) S[j] = 0.f;
  for (int s = 0; s < CH_; s++) {
    float vv = b2f(v[(tbase + s) * 512 + hh * 128 + tid]);
    const float4* e4p = (const float4*)&eL[s][0];
    const float4* k4p = (const float4*)&kL[s][0];
#pragma unroll
    for (int q = 0; q < 16; q++) {
      float4 e4 = e4p[q], k4 = k4p[q];
      S[4 * q + 0] = e4.x * S[4 * q + 0] + k4.x * vv;
      S[4 * q + 1] = e4.y * S[4 * q + 1] + k4.y * vv;
      S[4 * q + 2] = e4.z * S[4 * q + 2] + k4.z * vv;
      S[4 * q + 3] = e4.w * S[4 * q + 3] + k4.w * vv;
    }
  }
  size_t sbase = (size_t)blk * 8192;
#pragma unroll
  for (int j = 0; j < 64; j++) Sl[sbase + j * 128 + tid] = f2bs(S[j]);
  if (tid < 64) {
    float d = 1.f;
    for (int s = 0; s < CH_; s++) d *= eL[s][tid];
    Dp[(size_t)blk * 64 + tid] = d;
  }
}

__global__ __launch_bounds__(256) void wkv_scan(
    const unsigned short* __restrict__ Sl, const float* __restrict__ Dp,
    unsigned short* __restrict__ Ss)
{
  int e = blockIdx.x * 256 + threadIdx.x;   // < 32*8192
  int bh = e >> 13; int kv = e & 8191; int j = kv >> 7;
  float run = 0.f;
  for (int c = 0; c < NC_; c++) {
    size_t base = (size_t)bh * NC_ + c;
    Ss[base * 8192 + kv] = f2bs(run);
    run = Dp[base * 64 + j] * run + b2f(Sl[base * 8192 + kv]);
  }
}

__global__ __launch_bounds__(128) void wkv_pass3(
    const unsigned short* __restrict__ r, const unsigned short* __restrict__ k,
    const float* __restrict__ ew, const unsigned short* __restrict__ v,
    const float* __restrict__ rbk, const unsigned short* __restrict__ Ss,
    float* __restrict__ o)
{
  __shared__ float rL[CH_][64], kL[CH_][64], eL[CH_][64], rbL[CH_];
  int blk = blockIdx.x;
  int c = blk & (NC_ - 1), bh = blk >> 6;
  int b = bh >> 2, hh = bh & 3;
  int tid = threadIdx.x;
  size_t tbase = (size_t)b * T_ + (size_t)c * CH_;
  for (int idx = tid; idx < CH_ * 64; idx += 128) {
    int s = idx >> 6, j = idx & 63;
    size_t g = (tbase + s) * 256 + hh * 64 + j;
    rL[s][j] = b2f(r[g]); kL[s][j] = b2f(k[g]); eL[s][j] = ew[g];
  }
  if (tid < CH_) rbL[tid] = rbk[(tbase + tid) * 4 + hh];
  __syncthreads();
  float S[64];
  size_t sbase = (size_t)blk * 8192;
#pragma unroll
  for (int j = 0; j < 64; j++) S[j] = b2f(Ss[sbase + j * 128 + tid]);
  for (int s = 0; s < CH_; s++) {
    float vv = b2f(v[(tbase + s) * 512 + hh * 128 + tid]);
    float oa = rbL[s] * vv;
    const float4* r4p = (const float4*)&rL[s][0];
    const float4* e4p = (const float4*)&eL[s][0];
    const float4* k4p = (const float4*)&kL[s][0];
#pragma unroll
    for (int q = 0; q < 16; q++) {
      float4 r4 = r4p[q], e4 = e4p[q], k4 = k4p[q];
      oa += r4.x * S[4 * q + 0] + r4.y * S[4 * q + 1]
          + r4.z * S[4 * q + 2] + r4.w * S[4 * q + 3];
      S[4 * q + 0] = e4.x * S[4 * q + 0] + k4.x * vv;
      S[4 * q + 1] = e4.y * S[4 * q + 1] + k4.y * vv;
      S[4 * q + 2] = e4.z * S[4 * q + 2] + k4.z * vv;
      S[4 * q + 3] = e4.w * S[4 * q + 3] + k4.w * vv;
    }
    o[(tbase + s) * 512 + hh * 128 + tid] = oa;
  }
}

// --------------------------- groupnorm + swish gate -------------------------
__global__ __launch_bounds__(256) void gn_gate_kernel(
    const float* __restrict__ o, const float* __restrict__ g,
    const float* __restrict__ gg, const float* __restrict__ gb,
    unsigned short* __restrict__ obf)
{
  __shared__ float ov[512], ps[64], qs[64], mh[4], vh[4];
  int t = blockIdx.x, tid = threadIdx.x;
  size_t base = (size_t)t * 512;
  ov[tid] = o[base + tid]; ov[tid + 256] = o[base + 256 + tid];
  __syncthreads();
  if (tid < 64) {
    int hh = tid >> 4, sg = tid & 15;
    const float* p = &ov[hh * 128 + sg * 8];
    float s = 0.f, q = 0.f;
    for (int i = 0; i < 8; i++) { s += p[i]; q += p[i] * p[i]; }
    ps[tid] = s; qs[tid] = q;
  }
  __syncthreads();
  if (tid < 4) {
    float s = 0.f, q = 0.f;
    for (int i = 0; i < 16; i++) { s += ps[tid * 16 + i]; q += qs[tid * 16 + i]; }
    float m = s * (1.f / 128.f);
    mh[tid] = m; vh[tid] = q * (1.f / 128.f) - m * m;
  }
  __syncthreads();
  for (int c = tid; c < 512; c += 256) {
    int hh = c >> 7;
    float nrm = (ov[c] - mh[hh]) * rsqrtf(vh[hh] + EPS_);
    float gv = g[base + c];
    float sw = gv * (1.f / (1.f + expf(-gv)));
    obf[base + c] = f2bs((nrm * gg[c] + gb[c]) * sw);
  }
}

// ---------------------------------------------------------------------------
extern "C" void kernel_launch(void* const* d_in, const int* in_sizes, int n_in,
                              void* d_out, int out_size, void* d_ws, size_t ws_size,
                              hipStream_t stream) {
  (void)in_sizes; (void)n_in; (void)out_size; (void)ws_size;
  const float* x        = (const float*)d_in[0];
  const float* pre_g    = (const float*)d_in[1];
  const float* pre_b    = (const float*)d_in[2];
  const float* attn_g   = (const float*)d_in[3];
  const float* attn_b   = (const float*)d_in[4];
  const float* ffn_g    = (const float*)d_in[5];
  const float* ffn_b    = (const float*)d_in[6];
  const float* xproj_mu = (const float*)d_in[7];
  const float* xproj_w1 = (const float*)d_in[8];
  const float* xproj_w2 = (const float*)d_in[9];
  const float* x_bias   = (const float*)d_in[10];
  const float* r_W      = (const float*)d_in[11];
  const float* w_W1     = (const float*)d_in[12];
  const float* w_W2     = (const float*)d_in[13];
  const float* w_b      = (const float*)d_in[14];
  const float* k_W      = (const float*)d_in[15];
  const float* v_W      = (const float*)d_in[16];
  const float* g_W      = (const float*)d_in[17];
  const float* bonus    = (const float*)d_in[18];
  const float* gnorm_g  = (const float*)d_in[19];
  const float* gnorm_b  = (const float*)d_in[20];
  const float* o_W      = (const float*)d_in[21];
  const float* fk_mu    = (const float*)d_in[22];
  const float* fk_W     = (const float*)d_in[23];
  const float* fv_W     = (const float*)d_in[24];
  const float* fr_mu    = (const float*)d_in[25];
  const float* fr_W     = (const float*)d_in[26];

  const size_t BTH = (size_t)BT_ * 512;  // 4,194,304
  size_t cur = 0;
  auto alloc = [&](size_t bytes) { void* p = (char*)d_ws + cur; cur += (bytes + 255) & ~(size_t)255; return p; };
  float*          x0    = (float*)alloc(BTH * 4);
  unsigned short* hbufb = (unsigned short*)alloc(BTH * 2);
  unsigned short* m5b   = (unsigned short*)alloc(5 * BTH * 2);   // 40MB
  unsigned short* rbuf  = (unsigned short*)alloc((size_t)BT_ * 256 * 4);  // 8MB region
  unsigned short* kbuf  = (unsigned short*)alloc((size_t)BT_ * 256 * 4);  // 8MB region
  float*          ebuf  = (float*)alloc((size_t)BT_ * 256 * 4);  // 8MB
  unsigned short* vbuf  = (unsigned short*)alloc(BTH * 4);       // 16MB region
  float*          gbuf  = (float*)alloc(BTH * 4);                // 16MB
  unsigned short* wtmpb = (unsigned short*)alloc((size_t)BT_ * 128 * 2); // 2MB
  float*          rbk   = (float*)alloc((size_t)BT_ * 4 * 4);
  unsigned short* Sl    = (unsigned short*)alloc((size_t)2048 * 8192 * 2); // 32MB
  unsigned short* Ss    = (unsigned short*)alloc((size_t)2048 * 8192 * 2); // 32MB
  float*          Dp    = (float*)alloc((size_t)2048 * 64 * 4);  // 512KB
  float*          res   = (float*)alloc(BTH * 4);                // 16MB
  unsigned short* wpack = (unsigned short*)alloc((size_t)2621440 * 2);
  // aliases (occupant dead before writer runs):
  unsigned short* ybufb = rbuf;                    // dead before set A
  unsigned short* dlb   = vbuf;                    // dead before set A
  unsigned short* z5b   = (unsigned short*)gbuf;   // dead before set A
  float*          obuf  = (float*)m5b;             // m5 dead after set A
  unsigned short* obf16 = (unsigned short*)ebuf;   // ebuf dead after pass3
  float*          hf    = x0;                      // x0 dead after oW-RES
  unsigned short* mfk   = rbuf;                    // dead after pass3
  unsigned short* mfr   = kbuf;                    // dead after pass3
  unsigned short* kkb   = Sl;                      // Sl dead after scan
  float*          frtmp = (float*)vbuf;            // vbuf dead after pass3

  PackArgs pa;
  int off = 0, seg = 0;
  auto addseg = [&](const float* src, int rows, int cols, int dst_rows) {
    pa.s[seg] = {src, rows, cols, dst_rows};
    pa.base[seg] = off; off += dst_rows * cols; seg++;
  };
  addseg(xproj_w1, 160, 512, 192);   int o_w1p = pa.base[0];
  addseg(w_W1,      64, 512, 128);   int o_wW1 = pa.base[1];
  addseg(r_W,      256, 512, 256);   int o_rW  = pa.base[2];
  addseg(k_W,      256, 512, 256);   int o_kW  = pa.base[3];
  addseg(v_W,      512, 512, 512);   int o_vW  = pa.base[4];
  addseg(g_W,      512, 512, 512);   int o_gW  = pa.base[5];
  addseg(o_W,      512, 512, 512);   int o_oW  = pa.base[6];
  addseg(fk_W,    1024, 512, 1024);  int o_fkW = pa.base[7];
  addseg(fv_W,     512, 1024, 512);  int o_fvW = pa.base[8];
  addseg(fr_W,     512, 512, 512);   int o_frW = pa.base[9];
  addseg(w_W2,     256, 64, 256);    int o_wW2 = pa.base[10];
  addseg(xproj_w2, 512, 160, 512);   int o_xw2 = pa.base[11];
  pa.base[12] = off;

  pack_kernel<<<(off + 255) / 256, 256, 0, stream>>>(pa, wpack);
  ln2_kernel<<<BT_, 256, 0, stream>>>(x, pre_g, pre_b, attn_g, attn_b, x0, hbufb);
  ymix_kernel<<<BT_, 256, 0, stream>>>(hbufb, xproj_mu, ybufb, dlb);

  auto solo = [&](const unsigned short* A, const unsigned short* W, void* C,
                  const void* bias, const void* a1, const void* a2,
                  int N, int K, int lda, int ldw, int ldc, int epi) {
    GD<1> g; g.d[0] = {A, W, C, bias, a1, a2, N, K, lda, ldw, ldc, epi};
    mgemm<64, 64, 1><<<dim3(128, (N + 63) / 64, 1), 256, 0, stream>>>(g);
  };

  // z5 = tanh(Y @ W1p^T), N=192
  solo(ybufb, wpack + o_w1p, z5b, nullptr, nullptr, nullptr,
       192, 512, 512, 512, 192, EP_TANH_BF16);

  // xmix fused (replaces set B)
  xmix5_kernel<<<BT_ / TPB_, 256, 0, stream>>>(
      z5b, wpack + o_xw2, x_bias, hbufb, dlb, m5b);

  // set A: r, w1, k, v, g projections (K=512)
  {
    GD<5> g;
    g.d[0] = {m5b + 0 * BTH, wpack + o_rW, rbuf, nullptr, nullptr, nullptr, 256, 512, 512, 512, 256, EP_NONE_BF16};
    g.d[1] = {m5b + 1 * BTH, wpack + o_wW1, wtmpb, nullptr, nullptr, nullptr, 128, 512, 512, 512, 128, EP_TANH_BF16};
    g.d[2] = {m5b + 2 * BTH, wpack + o_kW, kbuf, nullptr, nullptr, nullptr, 256, 512, 512, 512, 256, EP_NONE_BF16};
    g.d[3] = {m5b + 3 * BTH, wpack + o_vW, vbuf, nullptr, nullptr, nullptr, 512, 512, 512, 512, 512, EP_NONE_BF16};
    g.d[4] = {m5b + 4 * BTH, wpack + o_gW, gbuf, nullptr, nullptr, nullptr, 512, 512, 512, 512, 512, EP_NONE_F32};
    mgemm<128, 128, 5><<<dim3(64, 4, 5), 256, 0, stream>>>(g);
  }

  // decay: ebuf = exp(-exp(wtmp @ w_W2^T + w_b)), K=64
  solo(wtmpb, wpack + o_wW2, ebuf, w_b, nullptr, nullptr,
       256, 64, 128, 64, 256, EP_EXPEXP_F32);

  rbk_kernel<<<BT_, 256, 0, stream>>>(rbuf, kbuf, bonus, rbk);
  wkv_pass1<<<2048, 128, 0, stream>>>(kbuf, ebuf, vbuf, Sl, Dp);
  wkv_scan<<<1024, 256, 0, stream>>>(Sl, Dp, Ss);
  wkv_pass3<<<2048, 128, 0, stream>>>(rbuf, kbuf, ebuf, vbuf, rbk, Ss, obuf);

  gn_gate_kernel<<<BT_, 256, 0, stream>>>(obuf, gbuf, gnorm_g, gnorm_b, obf16);

  // res = o @ o_W^T + x0
  solo(obf16, wpack + o_oW, res, nullptr, x0, nullptr,
       512, 512, 512, 512, 512, EP_RES_F32);

  ln1_kernel<<<BT_, 256, 0, stream>>>(res, ffn_g, ffn_b, hf);
  ffnmix_kernel<<<BT_, 256, 0, stream>>>(hf, fk_mu, fr_mu, mfk, mfr);

  // set C: fk (relu^2 -> kkb) and fr (-> frtmp), both K=512
  {
    GD<2> g;
    g.d[0] = {mfk, wpack + o_fkW, kkb, nullptr, nullptr, nullptr, 1024, 512, 512, 512, 1024, EP_RELU2_BF16};
    g.d[1] = {mfr, wpack + o_frW, frtmp, nullptr, nullptr, nullptr, 512, 512, 512, 512, 512, EP_NONE_F32};
    mgemm<128, 128, 2><<<dim3(64, 8, 2), 256, 0, stream>>>(g);
  }

  // out = res + sigmoid(frtmp) * (kk @ fv_W^T), K=1024
  solo(kkb, wpack + o_fvW, (float*)d_out, nullptr, res, frtmp,
       512, 1024, 1024, 1024, 512, EP_OUT2_F32);
}

// Round 7
// 360.830 us; speedup vs baseline: 3.7666x; 1.0024x over previous
//
#include <hip/hip_runtime.h>

// ---------------------------------------------------------------------------
// RWKV6 layer forward, MI355X. Round 6:
//  - xmix returns to the MFMA GEMM path (grouped, K=32) now that the
//    transposed vectorized epilogue exists (round-5's scatter is gone).
//    Kills the 70us VALU-bound xmix5 kernel (132 VGPR, 10% occupancy).
//  - gbuf stored bf16 (gate path) -> -16MB HBM traffic.
// ---------------------------------------------------------------------------

#define DEVINL __device__ __forceinline__

constexpr int B_  = 8, T_ = 1024;
constexpr int BT_ = B_ * T_;          // 8192 tokens
constexpr float EPS_ = 1e-5f;
constexpr int CH_ = 16;               // WKV chunk length
constexpr int NC_ = T_ / CH_;         // 64 chunks per sequence

typedef __bf16 bf16x8 __attribute__((ext_vector_type(8)));
typedef float  f32x4  __attribute__((ext_vector_type(4)));

DEVINL unsigned short f2bs(float f) { // fp32 -> bf16 bits, RNE
  union { float f; unsigned int i; } c; c.f = f;
  unsigned int x = c.i;
  return (unsigned short)((x + 0x7fffu + ((x >> 16) & 1u)) >> 16);
}
DEVINL float b2f(unsigned short u) {
  union { unsigned int i; float f; } c; c.i = ((unsigned int)u) << 16; return c.f;
}

DEVINL float block_sum256(float v, float* sb) {
  for (int o = 32; o; o >>= 1) v += __shfl_down(v, o);
  int w = threadIdx.x >> 6;
  __syncthreads();
  if ((threadIdx.x & 63) == 0) sb[w] = v;
  __syncthreads();
  return sb[0] + sb[1] + sb[2] + sb[3];
}

// --------------------------- weight pack ------------------------------------
struct PackSeg { const float* src; int rows, cols, dst_rows; };
struct PackArgs { PackSeg s[12]; int base[13]; };

__global__ __launch_bounds__(256) void pack_kernel(PackArgs pa, unsigned short* dst)
{
  int i = blockIdx.x * 256 + threadIdx.x;
  if (i >= pa.base[12]) return;
  int k = 0;
  while (i >= pa.base[k + 1]) k++;
  int loc = i - pa.base[k];
  PackSeg s = pa.s[k];
  int r = loc / s.cols, c = loc - r * s.cols;
  float v = (r < s.rows) ? s.src[(size_t)r * s.cols + c] : 0.f;
  dst[i] = f2bs(v);
}

// --------------------------- LN kernels ------------------------------------
__global__ __launch_bounds__(256) void ln2_kernel(
    const float* __restrict__ x,
    const float* __restrict__ pg, const float* __restrict__ pb,
    const float* __restrict__ ag, const float* __restrict__ ab,
    float* __restrict__ x0, unsigned short* __restrict__ h)
{
  __shared__ float sb[4];
  size_t base = (size_t)blockIdx.x * 512;
  int tid = threadIdx.x;
  float v0 = x[base + tid], v1 = x[base + 256 + tid];
  float m = block_sum256(v0 + v1, sb) * (1.f / 512.f);
  float d0 = v0 - m, d1 = v1 - m;
  float var = block_sum256(d0 * d0 + d1 * d1, sb) * (1.f / 512.f);
  float rs = rsqrtf(var + EPS_);
  float a0 = d0 * rs * pg[tid]       + pb[tid];
  float a1 = d1 * rs * pg[tid + 256] + pb[tid + 256];
  x0[base + tid] = a0; x0[base + 256 + tid] = a1;
  float m2 = block_sum256(a0 + a1, sb) * (1.f / 512.f);
  float e0 = a0 - m2, e1 = a1 - m2;
  float var2 = block_sum256(e0 * e0 + e1 * e1, sb) * (1.f / 512.f);
  float rs2 = rsqrtf(var2 + EPS_);
  h[base + tid]       = f2bs(e0 * rs2 * ag[tid]       + ab[tid]);
  h[base + 256 + tid] = f2bs(e1 * rs2 * ag[tid + 256] + ab[tid + 256]);
}

__global__ __launch_bounds__(256) void ln1_kernel(
    const float* __restrict__ in,
    const float* __restrict__ g, const float* __restrict__ b,
    float* __restrict__ out)
{
  __shared__ float sb[4];
  size_t base = (size_t)blockIdx.x * 512;
  int tid = threadIdx.x;
  float v0 = in[base + tid], v1 = in[base + 256 + tid];
  float m = block_sum256(v0 + v1, sb) * (1.f / 512.f);
  float d0 = v0 - m, d1 = v1 - m;
  float var = block_sum256(d0 * d0 + d1 * d1, sb) * (1.f / 512.f);
  float rs = rsqrtf(var + EPS_);
  out[base + tid]       = d0 * rs * g[tid]       + b[tid];
  out[base + 256 + tid] = d1 * rs * g[tid + 256] + b[tid + 256];
}

// --------------------------- mix kernels ------------------------------------
__global__ __launch_bounds__(256) void ymix_kernel(
    const unsigned short* __restrict__ h, const float* __restrict__ mu,
    unsigned short* __restrict__ y, unsigned short* __restrict__ dl)
{
  int t = blockIdx.x, tid = threadIdx.x, tt = t & (T_ - 1);
  size_t base = (size_t)t * 512;
  for (int c = tid; c < 512; c += 256) {
    float cur  = b2f(h[base + c]);
    float prev = tt ? b2f(h[base - 512 + c]) : 0.f;
    float d = prev - cur;
    dl[base + c] = f2bs(d);
    y[base + c] = f2bs(cur + d * mu[c]);
  }
}

__global__ __launch_bounds__(256) void ffnmix_kernel(
    const float* __restrict__ hf, const float* __restrict__ fkmu,
    const float* __restrict__ frmu,
    unsigned short* __restrict__ mfk, unsigned short* __restrict__ mfr)
{
  int t = blockIdx.x, tid = threadIdx.x, tt = t & (T_ - 1);
  size_t base = (size_t)t * 512;
  for (int c = tid; c < 512; c += 256) {
    float cur  = hf[base + c];
    float prev = tt ? hf[base - 512 + c] : 0.f;
    float d = prev - cur;
    mfk[base + c] = f2bs(cur + d * fkmu[c]);
    mfr[base + c] = f2bs(cur + d * frmu[c]);
  }
}

// --------------------------- MFMA GEMM v3 -----------------------------------
// C[M,N] = epi(A[M,K] @ W[N,K]^T). Transposed fragments: mfma(W,A) so each
// lane holds 4 consecutive n -> vectorized stores.
enum { EP_NONE_F32 = 0, EP_NONE_BF16 = 1, EP_TANH_BF16 = 2, EP_EXPEXP_F32 = 3,
       EP_RES_F32 = 4, EP_RELU2_BF16 = 5, EP_OUT2_F32 = 6, EP_XMIX_BF16 = 7 };

struct GemmDesc {
  const unsigned short* A; const unsigned short* W; void* C;
  const void* bias; const void* aux1; const void* aux2;
  int N, K, lda, ldw, ldc, epi;
};
template <int NG> struct GD { GemmDesc d[NG]; };

template <int BM, int BN, int NG>
__global__ __launch_bounds__(256) void mgemm(GD<NG> p)
{
  GemmDesc dd = p.d[blockIdx.z];
  int n0 = blockIdx.y * BN;
  if (n0 >= dd.N) return;
  int m0 = blockIdx.x * BM;
  constexpr int MFR = BM / 32, NFR = BN / 32;
  __shared__ short As[BM * 32];
  __shared__ short Ws[BN * 32];
  int tid = threadIdx.x, lane = tid & 63, wid = tid >> 6;
  int wm = wid >> 1, wn = wid & 1, lrow = lane & 15, lkg = lane >> 4;

  int arow, akg, wrow, wkg;
  if constexpr (BM == 128) { arow = tid >> 1; akg = (tid & 1) * 2; }
  else                     { arow = tid >> 2; akg = tid & 3; }
  if constexpr (BN == 128) { wrow = tid >> 1; wkg = (tid & 1) * 2; }
  else                     { wrow = tid >> 2; wkg = tid & 3; }
  int uA0 = (akg * (BM / 16) + (arow >> 4)) * 16 + (arow & 15);
  int uA1 = ((akg + 1) * (BM / 16) + (arow >> 4)) * 16 + (arow & 15);
  int uW0 = (wkg * (BN / 16) + (wrow >> 4)) * 16 + (wrow & 15);
  int uW1 = ((wkg + 1) * (BN / 16) + (wrow >> 4)) * 16 + (wrow & 15);

  f32x4 acc[MFR][NFR];
#pragma unroll
  for (int mf = 0; mf < MFR; mf++)
#pragma unroll
    for (int nf = 0; nf < NFR; nf++) acc[mf][nf] = (f32x4){0.f, 0.f, 0.f, 0.f};

  for (int kb = 0; kb < dd.K; kb += 32) {
    const int4* ap = (const int4*)(dd.A + (size_t)(m0 + arow) * dd.lda + kb + akg * 8);
    const int4* wp = (const int4*)(dd.W + (size_t)(n0 + wrow) * dd.ldw + kb + wkg * 8);
    int4 a0 = ap[0], w0 = wp[0], a1, w1;
    if constexpr (BM == 128) a1 = ap[1];
    if constexpr (BN == 128) w1 = wp[1];
    __syncthreads();
    *(int4*)&As[uA0 * 8] = a0;
    if constexpr (BM == 128) *(int4*)&As[uA1 * 8] = a1;
    *(int4*)&Ws[uW0 * 8] = w0;
    if constexpr (BN == 128) *(int4*)&Ws[uW1 * 8] = w1;
    __syncthreads();

    bf16x8 bfrag[NFR];
#pragma unroll
    for (int nf = 0; nf < NFR; nf++)
      bfrag[nf] = *(const bf16x8*)&Ws[((lkg * (BN / 16) + wn * NFR + nf) * 16 + lrow) * 8];
#pragma unroll
    for (int mf = 0; mf < MFR; mf++) {
      bf16x8 afrag = *(const bf16x8*)&As[((lkg * (BM / 16) + wm * MFR + mf) * 16 + lrow) * 8];
#pragma unroll
      for (int nf = 0; nf < NFR; nf++)
        acc[mf][nf] = __builtin_amdgcn_mfma_f32_16x16x32_bf16(
            bfrag[nf], afrag, acc[mf][nf], 0, 0, 0);   // D rows = n
    }
  }

#pragma unroll
  for (int mf = 0; mf < MFR; mf++) {
#pragma unroll
    for (int nf = 0; nf < NFR; nf++) {
      int m  = m0 + wm * (MFR * 16) + mf * 16 + lrow;
      int nb = n0 + wn * (NFR * 16) + nf * 16 + lkg * 4;
      size_t off = (size_t)m * dd.ldc + nb;
      float c0 = acc[mf][nf][0], c1 = acc[mf][nf][1];
      float c2 = acc[mf][nf][2], c3 = acc[mf][nf][3];
      switch (dd.epi) {
        case EP_NONE_F32: {
          f32x4 v = {c0, c1, c2, c3};
          *(f32x4*)((float*)dd.C + off) = v; break;
        }
        case EP_NONE_BF16: {
          uint2 u; u.x = f2bs(c0) | ((unsigned)f2bs(c1) << 16);
          u.y = f2bs(c2) | ((unsigned)f2bs(c3) << 16);
          *(uint2*)((unsigned short*)dd.C + off) = u; break;
        }
        case EP_TANH_BF16: {
          uint2 u; u.x = f2bs(tanhf(c0)) | ((unsigned)f2bs(tanhf(c1)) << 16);
          u.y = f2bs(tanhf(c2)) | ((unsigned)f2bs(tanhf(c3)) << 16);
          *(uint2*)((unsigned short*)dd.C + off) = u; break;
        }
        case EP_EXPEXP_F32: {
          const float* bi = (const float*)dd.bias;
          f32x4 v = {expf(-expf(c0 + bi[nb + 0])), expf(-expf(c1 + bi[nb + 1])),
                     expf(-expf(c2 + bi[nb + 2])), expf(-expf(c3 + bi[nb + 3]))};
          *(f32x4*)((float*)dd.C + off) = v; break;
        }
        case EP_RES_F32: {
          f32x4 a = *(const f32x4*)((const float*)dd.aux1 + off);
          f32x4 v = {c0 + a[0], c1 + a[1], c2 + a[2], c3 + a[3]};
          *(f32x4*)((float*)dd.C + off) = v; break;
        }
        case EP_RELU2_BF16: {
          c0 = fmaxf(c0, 0.f); c1 = fmaxf(c1, 0.f);
          c2 = fmaxf(c2, 0.f); c3 = fmaxf(c3, 0.f);
          uint2 u; u.x = f2bs(c0 * c0) | ((unsigned)f2bs(c1 * c1) << 16);
          u.y = f2bs(c2 * c2) | ((unsigned)f2bs(c3 * c3) << 16);
          *(uint2*)((unsigned short*)dd.C + off) = u; break;
        }
        case EP_OUT2_F32: {
          f32x4 rs = *(const f32x4*)((const float*)dd.aux1 + off);
          f32x4 fr = *(const f32x4*)((const float*)dd.aux2 + off);
          f32x4 v = {rs[0] + (1.f / (1.f + expf(-fr[0]))) * c0,
                     rs[1] + (1.f / (1.f + expf(-fr[1]))) * c1,
                     rs[2] + (1.f / (1.f + expf(-fr[2]))) * c2,
                     rs[3] + (1.f / (1.f + expf(-fr[3]))) * c3};
          *(f32x4*)((float*)dd.C + off) = v; break;
        }
        case EP_XMIX_BF16: {
          const float* bi = (const float*)dd.bias;
          uint2 hv = *(const uint2*)((const unsigned short*)dd.aux1 + off);
          uint2 dv = *(const uint2*)((const unsigned short*)dd.aux2 + off);
          const unsigned short* hu = (const unsigned short*)&hv;
          const unsigned short* du = (const unsigned short*)&dv;
          float r0 = b2f(hu[0]) + b2f(du[0]) * (c0 + bi[nb + 0]);
          float r1 = b2f(hu[1]) + b2f(du[1]) * (c1 + bi[nb + 1]);
          float r2 = b2f(hu[2]) + b2f(du[2]) * (c2 + bi[nb + 2]);
          float r3 = b2f(hu[3]) + b2f(du[3]) * (c3 + bi[nb + 3]);
          uint2 u; u.x = f2bs(r0) | ((unsigned)f2bs(r1) << 16);
          u.y = f2bs(r2) | ((unsigned)f2bs(r3) << 16);
          *(uint2*)((unsigned short*)dd.C + off) = u; break;
        }
      }
    }
  }
}

// --------------------------- bonus scalar ----------------------------------
__global__ __launch_bounds__(256) void rbk_kernel(
    const unsigned short* __restrict__ r, const unsigned short* __restrict__ k,
    const float* __restrict__ bonus, float* __restrict__ rbk)
{
  int t = blockIdx.x, tid = threadIdx.x;
  int hh = tid >> 6, j = tid & 63;
  size_t g = (size_t)t * 256 + hh * 64 + j;
  float p = b2f(r[g]) * b2f(k[g]) * bonus[hh * 64 + j];
  for (int o = 32; o; o >>= 1) p += __shfl_down(p, o);
  if (j == 0) rbk[(size_t)t * 4 + hh] = p;
}

// --------------------------- WKV 3-pass chunked scan (CH=16) ----------------
__global__ __launch_bounds__(128) void wkv_pass1(
    const unsigned short* __restrict__ k, const float* __restrict__ ew,
    const unsigned short* __restrict__ v, unsigned short* __restrict__ Sl,
    float* __restrict__ Dp)
{
  __shared__ float kL[CH_][64], eL[CH_][64];
  int blk = blockIdx.x;
  int c = blk & (NC_ - 1), bh = blk >> 6;
  int b = bh >> 2, hh = bh & 3;
  int tid = threadIdx.x;
  size_t tbase = (size_t)b * T_ + (size_t)c * CH_;
  for (int idx = tid; idx < CH_ * 64; idx += 128) {
    int s = idx >> 6, j = idx & 63;
    size_t g = (tbase + s) * 256 + hh * 64 + j;
    kL[s][j] = b2f(k[g]); eL[s][j] = ew[g];
  }
  __syncthreads();
  float S[64];
#pragma unroll
  for (int j = 0; j < 64; j++) S[j] = 0.f;
  for (int s = 0; s < CH_; s++) {
    float vv = b2f(v[(tbase + s) * 512 + hh * 128 + tid]);
    const float4* e4p = (const float4*)&eL[s][0];
    const float4* k4p = (const float4*)&kL[s][0];
#pragma unroll
    for (int q = 0; q < 16; q++) {
      float4 e4 = e4p[q], k4 = k4p[q];
      S[4 * q + 0] = e4.x * S[4 * q + 0] + k4.x * vv;
      S[4 * q + 1] = e4.y * S[4 * q + 1] + k4.y * vv;
      S[4 * q + 2] = e4.z * S[4 * q + 2] + k4.z * vv;
      S[4 * q + 3] = e4.w * S[4 * q + 3] + k4.w * vv;
    }
  }
  size_t sbase = (size_t)blk * 8192;
#pragma unroll
  for (int j = 0; j < 64; j++) Sl[sbase + j * 128 + tid] = f2bs(S[j]);
  if (tid < 64) {
    float d = 1.f;
    for (int s = 0; s < CH_; s++) d *= eL[s][tid];
    Dp[(size_t)blk * 64 + tid] = d;
  }
}

__global__ __launch_bounds__(256) void wkv_scan(
    const unsigned short* __restrict__ Sl, const float* __restrict__ Dp,
    unsigned short* __restrict__ Ss)
{
  int e = blockIdx.x * 256 + threadIdx.x;
  int bh = e >> 13; int kv = e & 8191; int j = kv >> 7;
  float run = 0.f;
  for (int c = 0; c < NC_; c++) {
    size_t base = (size_t)bh * NC_ + c;
    Ss[base * 8192 + kv] = f2bs(run);
    run = Dp[base * 64 + j] * run + b2f(Sl[base * 8192 + kv]);
  }
}

__global__ __launch_bounds__(128) void wkv_pass3(
    const unsigned short* __restrict__ r, const unsigned short* __restrict__ k,
    const float* __restrict__ ew, const unsigned short* __restrict__ v,
    const float* __restrict__ rbk, const unsigned short* __restrict__ Ss,
    float* __restrict__ o)
{
  __shared__ float rL[CH_][64], kL[CH_][64], eL[CH_][64], rbL[CH_];
  int blk = blockIdx.x;
  int c = blk & (NC_ - 1), bh = blk >> 6;
  int b = bh >> 2, hh = bh & 3;
  int tid = threadIdx.x;
  size_t tbase = (size_t)b * T_ + (size_t)c * CH_;
  for (int idx = tid; idx < CH_ * 64; idx += 128) {
    int s = idx >> 6, j = idx & 63;
    size_t g = (tbase + s) * 256 + hh * 64 + j;
    rL[s][j] = b2f(r[g]); kL[s][j] = b2f(k[g]); eL[s][j] = ew[g];
  }
  if (tid < CH_) rbL[tid] = rbk[(tbase + tid) * 4 + hh];
  __syncthreads();
  float S[64];
  size_t sbase = (size_t)blk * 8192;
#pragma unroll
  for (int j = 0; j < 64; j++) S[j] = b2f(Ss[sbase + j * 128 + tid]);
  for (int s = 0; s < CH_; s++) {
    float vv = b2f(v[(tbase + s) * 512 + hh * 128 + tid]);
    float oa = rbL[s] * vv;
    const float4* r4p = (const float4*)&rL[s][0];
    const float4* e4p = (const float4*)&eL[s][0];
    const float4* k4p = (const float4*)&kL[s][0];
#pragma unroll
    for (int q = 0; q < 16; q++) {
      float4 r4 = r4p[q], e4 = e4p[q], k4 = k4p[q];
      oa += r4.x * S[4 * q + 0] + r4.y * S[4 * q + 1]
          + r4.z * S[4 * q + 2] + r4.w * S[4 * q + 3];
      S[4 * q + 0] = e4.x * S[4 * q + 0] + k4.x * vv;
      S[4 * q + 1] = e4.y * S[4 * q + 1] + k4.y * vv;
      S[4 * q + 2] = e4.z * S[4 * q + 2] + k4.z * vv;
      S[4 * q + 3] = e4.w * S[4 * q + 3] + k4.w * vv;
    }
    o[(tbase + s) * 512 + hh * 128 + tid] = oa;
  }
}

// --------------------------- groupnorm + swish gate -------------------------
__global__ __launch_bounds__(256) void gn_gate_kernel(
    const float* __restrict__ o, const unsigned short* __restrict__ g,
    const float* __restrict__ gg, const float* __restrict__ gb,
    unsigned short* __restrict__ obf)
{
  __shared__ float ov[512], ps[64], qs[64], mh[4], vh[4];
  int t = blockIdx.x, tid = threadIdx.x;
  size_t base = (size_t)t * 512;
  ov[tid] = o[base + tid]; ov[tid + 256] = o[base + 256 + tid];
  __syncthreads();
  if (tid < 64) {
    int hh = tid >> 4, sg = tid & 15;
    const float* p = &ov[hh * 128 + sg * 8];
    float s = 0.f, q = 0.f;
    for (int i = 0; i < 8; i++) { s += p[i]; q += p[i] * p[i]; }
    ps[tid] = s; qs[tid] = q;
  }
  __syncthreads();
  if (tid < 4) {
    float s = 0.f, q = 0.f;
    for (int i = 0; i < 16; i++) { s += ps[tid * 16 + i]; q += qs[tid * 16 + i]; }
    float m = s * (1.f / 128.f);
    mh[tid] = m; vh[tid] = q * (1.f / 128.f) - m * m;
  }
  __syncthreads();
  for (int c = tid; c < 512; c += 256) {
    int hh = c >> 7;
    float nrm = (ov[c] - mh[hh]) * rsqrtf(vh[hh] + EPS_);
    float gv = b2f(g[base + c]);
    float sw = gv * (1.f / (1.f + expf(-gv)));
    obf[base + c] = f2bs((nrm * gg[c] + gb[c]) * sw);
  }
}

// ---------------------------------------------------------------------------
extern "C" void kernel_launch(void* const* d_in, const int* in_sizes, int n_in,
                              void* d_out, int out_size, void* d_ws, size_t ws_size,
                              hipStream_t stream) {
  (void)in_sizes; (void)n_in; (void)out_size; (void)ws_size;
  const float* x        = (const float*)d_in[0];
  const float* pre_g    = (const float*)d_in[1];
  const float* pre_b    = (const float*)d_in[2];
  const float* attn_g   = (const float*)d_in[3];
  const float* attn_b   = (const float*)d_in[4];
  const float* ffn_g    = (const float*)d_in[5];
  const float* ffn_b    = (const float*)d_in[6];
  const float* xproj_mu = (const float*)d_in[7];
  const float* xproj_w1 = (const float*)d_in[8];
  const float* xproj_w2 = (const float*)d_in[9];
  const float* x_bias   = (const float*)d_in[10];
  const float* r_W      = (const float*)d_in[11];
  const float* w_W1     = (const float*)d_in[12];
  const float* w_W2     = (const float*)d_in[13];
  const float* w_b      = (const float*)d_in[14];
  const float* k_W      = (const float*)d_in[15];
  const float* v_W      = (const float*)d_in[16];
  const float* g_W      = (const float*)d_in[17];
  const float* bonus    = (const float*)d_in[18];
  const float* gnorm_g  = (const float*)d_in[19];
  const float* gnorm_b  = (const float*)d_in[20];
  const float* o_W      = (const float*)d_in[21];
  const float* fk_mu    = (const float*)d_in[22];
  const float* fk_W     = (const float*)d_in[23];
  const float* fv_W     = (const float*)d_in[24];
  const float* fr_mu    = (const float*)d_in[25];
  const float* fr_W     = (const float*)d_in[26];

  const size_t BTH = (size_t)BT_ * 512;  // 4,194,304
  size_t cur = 0;
  auto alloc = [&](size_t bytes) { void* p = (char*)d_ws + cur; cur += (bytes + 255) & ~(size_t)255; return p; };
  float*          x0    = (float*)alloc(BTH * 4);
  unsigned short* hbufb = (unsigned short*)alloc(BTH * 2);
  unsigned short* m5b   = (unsigned short*)alloc(5 * BTH * 2);   // 40MB
  unsigned short* rbuf  = (unsigned short*)alloc((size_t)BT_ * 256 * 4);
  unsigned short* kbuf  = (unsigned short*)alloc((size_t)BT_ * 256 * 4);
  float*          ebuf  = (float*)alloc((size_t)BT_ * 256 * 4);
  unsigned short* vbuf  = (unsigned short*)alloc(BTH * 4);
  unsigned short* gbuf  = (unsigned short*)alloc(BTH * 4);
  unsigned short* wtmpb = (unsigned short*)alloc((size_t)BT_ * 128 * 2);
  float*          rbk   = (float*)alloc((size_t)BT_ * 4 * 4);
  unsigned short* Sl    = (unsigned short*)alloc((size_t)2048 * 8192 * 2);
  unsigned short* Ss    = (unsigned short*)alloc((size_t)2048 * 8192 * 2);
  float*          Dp    = (float*)alloc((size_t)2048 * 64 * 4);
  float*          res   = (float*)alloc(BTH * 4);
  unsigned short* wpack = (unsigned short*)alloc((size_t)2621440 * 2);
  // aliases (occupant dead before writer runs):
  unsigned short* ybufb = rbuf;
  unsigned short* dlb   = vbuf;
  unsigned short* z5b   = gbuf;
  float*          obuf  = (float*)m5b;
  unsigned short* obf16 = (unsigned short*)ebuf;
  float*          hf    = x0;
  unsigned short* mfk   = rbuf;
  unsigned short* mfr   = kbuf;
  unsigned short* kkb   = Sl;
  float*          frtmp = (float*)vbuf;

  PackArgs pa;
  int off = 0, seg = 0;
  auto addseg = [&](const float* src, int rows, int cols, int dst_rows) {
    pa.s[seg] = {src, rows, cols, dst_rows};
    pa.base[seg] = off; off += dst_rows * cols; seg++;
  };
  addseg(xproj_w1, 160, 512, 192);   int o_w1p = pa.base[0];
  addseg(w_W1,      64, 512, 128);   int o_wW1 = pa.base[1];
  addseg(r_W,      256, 512, 256);   int o_rW  = pa.base[2];
  addseg(k_W,      256, 512, 256);   int o_kW  = pa.base[3];
  addseg(v_W,      512, 512, 512);   int o_vW  = pa.base[4];
  addseg(g_W,      512, 512, 512);   int o_gW  = pa.base[5];
  addseg(o_W,      512, 512, 512);   int o_oW  = pa.base[6];
  addseg(fk_W,    1024, 512, 1024);  int o_fkW = pa.base[7];
  addseg(fv_W,     512, 1024, 512);  int o_fvW = pa.base[8];
  addseg(fr_W,     512, 512, 512);   int o_frW = pa.base[9];
  addseg(w_W2,     256, 64, 256);    int o_wW2 = pa.base[10];
  addseg(xproj_w2, 512, 160, 512);   int o_xw2 = pa.base[11];
  pa.base[12] = off;

  pack_kernel<<<(off + 255) / 256, 256, 0, stream>>>(pa, wpack);
  ln2_kernel<<<BT_, 256, 0, stream>>>(x, pre_g, pre_b, attn_g, attn_b, x0, hbufb);
  ymix_kernel<<<BT_, 256, 0, stream>>>(hbufb, xproj_mu, ybufb, dlb);

  auto solo = [&](const unsigned short* A, const unsigned short* W, void* C,
                  const void* bias, const void* a1, const void* a2,
                  int N, int K, int lda, int ldw, int ldc, int epi) {
    GD<1> g; g.d[0] = {A, W, C, bias, a1, a2, N, K, lda, ldw, ldc, epi};
    mgemm<64, 64, 1><<<dim3(128, (N + 63) / 64, 1), 256, 0, stream>>>(g);
  };

  // z5 = tanh(Y @ W1p^T), N=192
  solo(ybufb, wpack + o_w1p, z5b, nullptr, nullptr, nullptr,
       192, 512, 512, 512, 192, EP_TANH_BF16);

  // xmix as grouped GEMM (K=32), vectorized EP_XMIX_BF16 epilogue
  {
    GD<5> g;
    for (int n = 0; n < 5; n++)
      g.d[n] = {z5b + n * 32, wpack + o_xw2 + n * 32, m5b + (size_t)n * BTH,
                x_bias + n * 512, hbufb, dlb, 512, 32, 192, 160, 512, EP_XMIX_BF16};
    mgemm<128, 128, 5><<<dim3(64, 4, 5), 256, 0, stream>>>(g);
  }

  // set A: r, w1, k, v, g projections (K=512)
  {
    GD<5> g;
    g.d[0] = {m5b + 0 * BTH, wpack + o_rW, rbuf, nullptr, nullptr, nullptr, 256, 512, 512, 512, 256, EP_NONE_BF16};
    g.d[1] = {m5b + 1 * BTH, wpack + o_wW1, wtmpb, nullptr, nullptr, nullptr, 128, 512, 512, 512, 128, EP_TANH_BF16};
    g.d[2] = {m5b + 2 * BTH, wpack + o_kW, kbuf, nullptr, nullptr, nullptr, 256, 512, 512, 512, 256, EP_NONE_BF16};
    g.d[3] = {m5b + 3 * BTH, wpack + o_vW, vbuf, nullptr, nullptr, nullptr, 512, 512, 512, 512, 512, EP_NONE_BF16};
    g.d[4] = {m5b + 4 * BTH, wpack + o_gW, gbuf, nullptr, nullptr, nullptr, 512, 512, 512, 512, 512, EP_NONE_BF16};
    mgemm<128, 128, 5><<<dim3(64, 4, 5), 256, 0, stream>>>(g);
  }

  // decay: ebuf = exp(-exp(wtmp @ w_W2^T + w_b)), K=64
  solo(wtmpb, wpack + o_wW2, ebuf, w_b, nullptr, nullptr,
       256, 64, 128, 64, 256, EP_EXPEXP_F32);

  rbk_kernel<<<BT_, 256, 0, stream>>>(rbuf, kbuf, bonus, rbk);
  wkv_pass1<<<2048, 128, 0, stream>>>(kbuf, ebuf, vbuf, Sl, Dp);
  wkv_scan<<<1024, 256, 0, stream>>>(Sl, Dp, Ss);
  wkv_pass3<<<2048, 128, 0, stream>>>(rbuf, kbuf, ebuf, vbuf, rbk, Ss, obuf);

  gn_gate_kernel<<<BT_, 256, 0, stream>>>(obuf, gbuf, gnorm_g, gnorm_b, obf16);

  // res = o @ o_W^T + x0
  solo(obf16, wpack + o_oW, res, nullptr, x0, nullptr,
       512, 512, 512, 512, 512, EP_RES_F32);

  ln1_kernel<<<BT_, 256, 0, stream>>>(res, ffn_g, ffn_b, hf);
  ffnmix_kernel<<<BT_, 256, 0, stream>>>(hf, fk_mu, fr_mu, mfk, mfr);

  // set C: fk (relu^2 -> kkb) and fr (-> frtmp), both K=512
  {
    GD<2> g;
    g.d[0] = {mfk, wpack + o_fkW, kkb, nullptr, nullptr, nullptr, 1024, 512, 512, 512, 1024, EP_RELU2_BF16};
    g.d[1] = {mfr, wpack + o_frW, frtmp, nullptr, nullptr, nullptr, 512, 512, 512, 512, 512, EP_NONE_F32};
    mgemm<128, 128, 2><<<dim3(64, 8, 2), 256, 0, stream>>>(g);
  }

  // out = res + sigmoid(frtmp) * (kk @ fv_W^T), K=1024
  solo(kkb, wpack + o_fvW, (float*)d_out, nullptr, res, frtmp,
       512, 1024, 1024, 1024, 512, EP_OUT2_F32);
}